// Round 18
// baseline (362.626 us; speedup 1.0000x reference)
//
#include <hip/hip_runtime.h>

#define T_SEQ 2048
#define NH    6
#define HD    128
#define CDIM  768
#define NQKV  2304
#define MROWS 8192   // B*T = 4*2048
#define NSLOT 1104   // 46 chunks per (b,h) * 24
// 1/sqrt(128) * log2(e): folded into Q during gemm1 epilogue
#define QSCL  0.12754011021989615f

typedef __attribute__((ext_vector_type(8)))  short bf16x8;
typedef __attribute__((ext_vector_type(4)))  float f32x4;
typedef __attribute__((ext_vector_type(16))) float f32x16;
typedef __attribute__((ext_vector_type(2)))  int   i32x2;

__device__ __forceinline__ unsigned short f2bf(float f){
  unsigned int u = __builtin_bit_cast(unsigned int, f);
  u += 0x7fffu + ((u >> 16) & 1u);          // round-to-nearest-even
  return (unsigned short)(u >> 16);
}
__device__ __forceinline__ float bf2f(unsigned short h){
  unsigned int u = ((unsigned int)h) << 16;
  return __builtin_bit_cast(float, u);
}
// raw v_exp_f32: computes 2^x in one instruction (no libm slow path)
__device__ __forceinline__ float ex2(float x){
  return __builtin_amdgcn_exp2f(x);
}
// pack 2 f32 -> 2 bf16 in one instr
__device__ __forceinline__ unsigned int cvtpk(float lo, float hi){
  unsigned int r;
  asm("v_cvt_pk_bf16_f32 %0, %1, %2" : "=v"(r) : "v"(lo), "v"(hi));
  return r;
}

// async global->LDS, 16B per lane; LDS dest is wave-uniform base + lane*16
__device__ __forceinline__ void gload_lds16(const void* g, void* l){
  __builtin_amdgcn_global_load_lds(
      (const __attribute__((address_space(1))) unsigned int*)g,
      (__attribute__((address_space(3))) unsigned int*)l, 16, 0, 0);
}

// chunking: q-block Q (QBLK=128) has 2Q+2 tiles of 64; nc = ceil((2Q+2)/7)
__device__ __forceinline__ int ncq(int Q){
  return Q < 3 ? 1 : Q < 7 ? 2 : Q < 10 ? 3 : Q < 14 ? 4 : 5;
}
// chunks before q-block Q
__device__ __forceinline__ int cumc(int Q){
  return Q < 4 ? Q : Q < 8 ? 3 + 2*(Q-3) : Q < 11 ? 11 + 3*(Q-7)
       : Q < 15 ? 20 + 4*(Q-10) : 36 + 5*(Q-14);
}

// ---------------- f32 -> bf16 conversion (vectorized) ----------------
__global__ __launch_bounds__(256) void cvt_f32_bf16(
    const float* __restrict__ in, unsigned short* __restrict__ out, int n4){
  int i = blockIdx.x * 256 + threadIdx.x;
  if (i >= n4) return;
  float4 v = reinterpret_cast<const float4*>(in)[i];
  ushort4 o;
  o.x = f2bf(v.x); o.y = f2bf(v.y); o.z = f2bf(v.z); o.w = f2bf(v.w);
  reinterpret_cast<ushort4*>(out)[i] = o;
}

// 4 weight matrices (each CDIM*CDIM f32) -> contiguous bf16 (Wqkv then Wo)
__global__ __launch_bounds__(256) void cvt_w4(
    const float* __restrict__ w0, const float* __restrict__ w1,
    const float* __restrict__ w2, const float* __restrict__ w3,
    unsigned short* __restrict__ out){
  const int which = blockIdx.y;
  const float* src = which == 0 ? w0 : which == 1 ? w1 : which == 2 ? w2 : w3;
  int i = blockIdx.x * 256 + threadIdx.x;           // in float4 units
  float4 v = reinterpret_cast<const float4*>(src)[i];
  ushort4 o;
  o.x = f2bf(v.x); o.y = f2bf(v.y); o.z = f2bf(v.z); o.w = f2bf(v.w);
  reinterpret_cast<ushort4*>(out + (size_t)which * CDIM * CDIM)[i] = o;
}

// ---------------- GEMM: C = A(MxK,bf16) * B(NxK,bf16)^T ----------------
// 128x128 tile, BK=64, global_load_lds(16B) into linear LDS, XOR slot-swizzle
// both-sides. Waves own 32 ROWS x 128 cols (acc[2][8]); EPI=1 fuses
// RoPE+RMSNorm for q/k col-tiles of QKV (Q additionally pre-scaled by
// 1/sqrt(128)*log2e so attention softmax runs in exp2 domain) and
// TRANSPOSES V col-tiles into Vt via LDS bounce.
template<int EPI>
__global__ __launch_bounds__(256) void gemm_bt(
    const unsigned short* __restrict__ A,
    const unsigned short* __restrict__ B,
    void* __restrict__ Cv, int M, int N, int K,
    const float* __restrict__ cosp, const float* __restrict__ sinp,
    unsigned short* __restrict__ Vt)
{
  __shared__ unsigned short sh[128 * 128];  // As = sh[0:8192), Bs = sh[8192:)
  unsigned short* As = sh;
  unsigned short* Bs = sh + 128 * 64;
  const int tid  = threadIdx.x;
  const int lane = tid & 63;
  const int wave = tid >> 6;
  const int lr = lane & 15, lg = lane >> 4;
  const int srow = lane >> 3;               // staging row within 8-row seg
  const int sslot = (lane & 7) ^ (lane >> 3);  // pre-swizzled global slot
  // XCD-aware swizzle; within an XCD, col-tiles vary fastest (A-panel reuse)
  const int gx = gridDim.x, gy = gridDim.y, nwg = gx * gy;
  const int flat = blockIdx.y * gx + blockIdx.x;
  const int nf = (flat & 7) * (nwg >> 3) + (flat >> 3);
  const int row0 = (nf / gy) * 128, col0 = (nf % gy) * 128;
  const int wrow = wave * 32;               // wave's row base within tile

  f32x4 acc[2][8];
  const f32x4 z = {0.f, 0.f, 0.f, 0.f};
  #pragma unroll
  for (int i = 0; i < 2; ++i)
    #pragma unroll
    for (int j = 0; j < 8; ++j) acc[i][j] = z;

  for (int k0 = 0; k0 < K; k0 += 64){
    #pragma unroll
    for (int i = 0; i < 4; ++i){
      int seg = wave * 4 + i;                 // 8 rows per 1KB segment
      int r = seg * 8 + srow;
      gload_lds16(&A[(size_t)(row0 + r) * K + k0 + sslot * 8], &As[seg * 512]);
      gload_lds16(&B[(size_t)(col0 + r) * K + k0 + sslot * 8], &Bs[seg * 512]);
    }
    __syncthreads();
    #pragma unroll
    for (int kk = 0; kk < 64; kk += 32){
      bf16x8 af[2], bfr[8];
      #pragma unroll
      for (int mi = 0; mi < 2; ++mi)
        af[mi] = *reinterpret_cast<const bf16x8*>(
            &As[(wrow + mi*16 + lr) * 64 + ((((kk>>3) + lg) ^ (lr & 7)) * 8)]);
      #pragma unroll
      for (int ni = 0; ni < 8; ++ni)
        bfr[ni] = *reinterpret_cast<const bf16x8*>(
            &Bs[(ni*16 + lr) * 64 + ((((kk>>3) + lg) ^ (lr & 7)) * 8)]);
      #pragma unroll
      for (int mi = 0; mi < 2; ++mi)
        #pragma unroll
        for (int ni = 0; ni < 8; ++ni)
          acc[mi][ni] = __builtin_amdgcn_mfma_f32_16x16x32_bf16(af[mi], bfr[ni], acc[mi][ni], 0, 0, 0);
    }
    __syncthreads();
  }

  if (EPI == 0){
    float* Cf = reinterpret_cast<float*>(Cv);
    #pragma unroll
    for (int mi = 0; mi < 2; ++mi)
      #pragma unroll
      for (int ni = 0; ni < 8; ++ni)
        #pragma unroll
        for (int r = 0; r < 4; ++r)
          Cf[(size_t)(row0 + wrow + mi*16 + lg*4 + r) * N + col0 + ni*16 + lr] = acc[mi][ni][r];
  } else {
    unsigned short* Cb = reinterpret_cast<unsigned short*>(Cv);
    const int ct = col0 >> 7;               // 0..17
    if (ct >= 12){
      // V tile: transpose via LDS bounce -> Vt[(b,h)][d][t]
      const int hh = ct - 12;
      const int b2 = row0 >> 11, t0 = row0 & (T_SEQ - 1);
      #pragma unroll
      for (int mi = 0; mi < 2; ++mi)
        #pragma unroll
        for (int ni = 0; ni < 8; ++ni)
          #pragma unroll
          for (int r = 0; r < 4; ++r){
            const int trow = wrow + mi*16 + lg*4 + r;
            const int col  = ni*16 + lr;
            sh[trow * 128 + (col ^ ((trow & 7) << 4))] = f2bf(acc[mi][ni][r]);
          }
      __syncthreads();
      const int dd = tid >> 1, tq = (tid & 1) * 64;
      unsigned short* dst =
          Vt + ((size_t)(b2 * NH + hh) * HD + dd) * T_SEQ + t0 + tq;
      #pragma unroll
      for (int j8 = 0; j8 < 8; ++j8){
        union { int4 v; unsigned short u[8]; } w;
        #pragma unroll
        for (int jj = 0; jj < 8; ++jj){
          const int tt = tq + j8 * 8 + jj;     // (tt & 7) == jj
          w.u[jj] = sh[tt * 128 + (dd ^ (jj << 4))];
        }
        *reinterpret_cast<int4*>(&dst[j8 * 8]) = w.v;
      }
    } else {
      // Q or K: RoPE (pairs d, d+64 = ni, ni+4) + RMSNorm over 128, then bf16
      // Q tiles (ct<6) additionally scaled by QSCL (softmax exp2-domain)
      const float post = (ct < 6) ? QSCL : 1.0f;
      #pragma unroll
      for (int mi = 0; mi < 2; ++mi){
        #pragma unroll
        for (int r = 0; r < 4; ++r){
          const int row = row0 + wrow + mi*16 + lg*4 + r;
          const int t = row & (T_SEQ - 1);
          float y1[4], y2[4], ssp = 0.f;
          #pragma unroll
          for (int ni = 0; ni < 4; ++ni){
            const int d = ni*16 + lr;
            float c = cosp[t * 64 + d];
            float s = sinp[t * 64 + d];
            float x1 = acc[mi][ni][r], x2 = acc[mi][ni+4][r];
            y1[ni] = x1 * c + x2 * s;
            y2[ni] = x2 * c - x1 * s;
            ssp += y1[ni]*y1[ni] + y2[ni]*y2[ni];
          }
          #pragma unroll
          for (int off = 1; off < 16; off <<= 1) ssp += __shfl_xor(ssp, off);
          const float inv = rsqrtf(ssp * (1.0f / 128.0f) + 1e-15f) * post;
          #pragma unroll
          for (int ni = 0; ni < 4; ++ni){
            const int d = ni*16 + lr;
            Cb[(size_t)row * N + col0 + d]      = f2bf(y1[ni] * inv);
            Cb[(size_t)row * N + col0 + d + 64] = f2bf(y2[ni] * inv);
          }
        }
      }
    }
  }
}

// ---------------- causal flash attention: 32x32 swapped-operand, balanced split-KV ----------------
// 4 waves x 32 q-rows (QBLK=128), KVBLK=64, chunks of <=7 tiles -> 1104 blocks.
// ZERO-VGPR staging via global_load_lds into LINEAR LDS with both-sides XOR
// slot swizzle (slot ^= row&7; ~4-way residual conflicts). Dropping the
// reg-staged prefetch cuts VGPR below the 128 cliff -> 4 waves/SIMD ->
// 4 blocks/CU resident (2x TLP). __launch_bounds__(256,4) pins it.
// Q pre-scaled by 1/sqrt(128)*log2e -> softmax via raw v_exp_f32.
__global__ __launch_bounds__(256, 4) void attn_fwd(
    const unsigned short* __restrict__ QKVb,   // rope'd Q,K in place
    const unsigned short* __restrict__ Vt,     // (B*H, D, T)
    unsigned short* __restrict__ AO,
    unsigned short* __restrict__ Op, float* __restrict__ Mp, float* __restrict__ Lp)
{
  __shared__ unsigned short Ks[64 * 128];   // linear, rows 256B, swizzled slots
  __shared__ unsigned short Vs[128 * 64];   // linear, rows 128B, swizzled slots
  const int tid = threadIdx.x;
  const int lane = tid & 63, wave = tid >> 6;
  const int l31 = lane & 31, hi = lane >> 5;

  // XCD-aware remap: 1104 blocks, 138/XCD = 3 heads' 46 chunks each
  const int flat = blockIdx.x;
  const int nf = (flat & 7) * 138 + (flat >> 3);
  const int bh = nf / 46;
  const int L = 45 - (nf % 46);              // big chunks first within XCD
  int Q, c;
  if (L < 3)      { Q = L; c = 0; }
  else if (L < 11){ int m = L - 3;  Q = 3 + (m >> 1);  c = m & 1; }
  else if (L < 20){ int m = L - 11; Q = 7 + m / 3;     c = m % 3; }
  else if (L < 36){ int m = L - 20; Q = 10 + (m >> 2); c = m & 3; }
  else            { int m = L - 36; Q = 14 + m / 5;    c = m % 5; }
  const int nc = ncq(Q);
  const int tiles = 2 * Q + 2;
  const int base = tiles / nc, rem = tiles % nc;
  const int tbeg = c * base + (c < rem ? c : rem);
  const int tend = tbeg + base + (c < rem ? 1 : 0);
  const int b = bh / NH, h = bh % NH;
  const int qw = Q * 128 + wave * 32;

  const unsigned short* Qp = QKVb + (size_t)(b * T_SEQ) * NQKV + h * HD;
  const unsigned short* Kp = QKVb + (size_t)(b * T_SEQ) * NQKV + CDIM + h * HD;
  const unsigned short* Vp = Vt + (size_t)bh * HD * T_SEQ;

  // staging: K seg = 4 rows x 16 slots; V seg = 8 rows x 8 slots (1KB each)
  const int krow_in = lane >> 4;                 // 0..3
  const int kslot   = lane & 15;
  const int vrow_in = lane >> 3;                 // 0..7
  const int vslot   = lane & 7;

  // Q B-frags: B[k=8hi+j][n=l31] = Q[q=qw+l31][d=16c4+8hi+j]
  bf16x8 qf[8];
  #pragma unroll
  for (int c4 = 0; c4 < 8; ++c4)
    qf[c4] = *reinterpret_cast<const bf16x8*>(
        &Qp[(size_t)(qw + l31) * NQKV + c4 * 16 + hi * 8]);

  f32x16 o[4];
  #pragma unroll
  for (int db = 0; db < 4; ++db)
    #pragma unroll
    for (int r = 0; r < 16; ++r) o[db][r] = 0.f;
  float mrun = -__builtin_inff(), lrun = 0.f;   // mrun in log2 domain

  for (int t = tbeg; t < tend; ++t){
    const int kv0 = t * 64;
    // ---- stage K and V via global_load_lds (0 VGPR); source pre-swizzled ----
    #pragma unroll
    for (int i = 0; i < 4; ++i){
      const int kseg = wave * 4 + i;
      const int krow = kseg * 4 + krow_in;
      const int kgs  = kslot ^ (krow & 7);
      gload_lds16(Kp + (size_t)(kv0 + krow) * NQKV + kgs * 8, &Ks[kseg * 512]);
      const int vseg = wave * 4 + i;
      const int vrow = vseg * 8 + vrow_in;
      const int vgs  = vslot ^ (vrow & 7);
      gload_lds16(Vp + (size_t)vrow * T_SEQ + kv0 + vgs * 8, &Vs[vseg * 512]);
    }
    __syncthreads();                        // drains vmcnt: tile staged

    if (kv0 <= qw + 31){                     // tile has unmasked work for this wave
      // ---- S^T = K Q^T (Q pre-scaled): lane holds S[kv][q=qw+l31] ----
      f32x16 s[2];
      #pragma unroll
      for (int r = 0; r < 16; ++r){ s[0][r] = 0.f; s[1][r] = 0.f; }
      __builtin_amdgcn_s_setprio(1);
      #pragma unroll
      for (int c4 = 0; c4 < 8; ++c4){
        const int ksl = (c4 * 2 + hi) ^ (l31 & 7);   // swizzled slot
        bf16x8 k0 = *reinterpret_cast<const bf16x8*>(&Ks[(l31) * 128 + ksl * 8]);
        bf16x8 k1 = *reinterpret_cast<const bf16x8*>(&Ks[(32 + l31) * 128 + ksl * 8]);
        s[0] = __builtin_amdgcn_mfma_f32_32x32x16_bf16(k0, qf[c4], s[0], 0, 0, 0);
        s[1] = __builtin_amdgcn_mfma_f32_32x32x16_bf16(k1, qf[c4], s[1], 0, 0, 0);
      }
      __builtin_amdgcn_s_setprio(0);

      // ---- causal mask (diagonal tiles only; interior: no scale work) ----
      const int qg = qw + l31;
      if (kv0 + 63 > qw){
        #pragma unroll
        for (int blk = 0; blk < 2; ++blk)
          #pragma unroll
          for (int r = 0; r < 16; ++r){
            int kg = kv0 + 32 * blk + (r & 3) + 8 * (r >> 2) + 4 * hi;
            s[blk][r] = (kg <= qg) ? s[blk][r] : -__builtin_inff();
          }
      }

      // ---- row max: tree over own 32 + 1 cross-half shuffle ----
      float t8[8];
      #pragma unroll
      for (int blk = 0; blk < 2; ++blk)
        #pragma unroll
        for (int j = 0; j < 4; ++j)
          t8[blk * 4 + j] = fmaxf(fmaxf(s[blk][4*j], s[blk][4*j+1]),
                                  fmaxf(s[blk][4*j+2], s[blk][4*j+3]));
      float pm = fmaxf(fmaxf(fmaxf(t8[0], t8[1]), fmaxf(t8[2], t8[3])),
                       fmaxf(fmaxf(t8[4], t8[5]), fmaxf(t8[6], t8[7])));
      pm = fmaxf(pm, __shfl_xor(pm, 32));

      // ---- deferred rescale (wave-uniform; exp2 domain, raw v_exp) ----
      if (__any(pm > mrun)){
        float mn = fmaxf(mrun, pm);
        float scf = (mrun == -__builtin_inff()) ? 0.f : ex2(mrun - mn);
        mrun = mn; lrun *= scf;
        #pragma unroll
        for (int r = 0; r < 16; ++r){
          float scr = __shfl(scf, (r & 3) + 8 * (r >> 2) + 4 * hi, 32);
          #pragma unroll
          for (int db = 0; db < 4; ++db) o[db][r] *= scr;
        }
      }

      // ---- exp2 (raw v_exp_f32) + row sum ----
      float a8[8];
      #pragma unroll
      for (int blk = 0; blk < 2; ++blk)
        #pragma unroll
        for (int j = 0; j < 4; ++j){
          float p0 = ex2(s[blk][4*j]   - mrun);
          float p1 = ex2(s[blk][4*j+1] - mrun);
          float p2 = ex2(s[blk][4*j+2] - mrun);
          float p3 = ex2(s[blk][4*j+3] - mrun);
          s[blk][4*j] = p0; s[blk][4*j+1] = p1; s[blk][4*j+2] = p2; s[blk][4*j+3] = p3;
          a8[blk * 4 + j] = (p0 + p1) + (p2 + p3);
        }
      float ls = ((a8[0] + a8[1]) + (a8[2] + a8[3])) + ((a8[4] + a8[5]) + (a8[6] + a8[7]));
      lrun += ls + __shfl_xor(ls, 32);

      // ---- O += P V : A-frags via cvt_pk + permlane32_swap ----
      __builtin_amdgcn_s_setprio(1);
      #pragma unroll
      for (int kc = 0; kc < 4; ++kc){
        const int blk = kc >> 1, base2 = (kc & 1) * 8;
        unsigned int a0 = cvtpk(s[blk][base2+0], s[blk][base2+1]);
        unsigned int b0 = cvtpk(s[blk][base2+4], s[blk][base2+5]);
        unsigned int a1 = cvtpk(s[blk][base2+2], s[blk][base2+3]);
        unsigned int b1 = cvtpk(s[blk][base2+6], s[blk][base2+7]);
        i32x2 sw0 = __builtin_amdgcn_permlane32_swap((int)a0, (int)b0, false, false);
        i32x2 sw1 = __builtin_amdgcn_permlane32_swap((int)a1, (int)b1, false, false);
        union { bf16x8 v; unsigned int u[4]; } pa;
        pa.u[0] = (unsigned int)sw0[0];   // kv 8hi+{0,1}
        pa.u[1] = (unsigned int)sw1[0];   // kv 8hi+{2,3}
        pa.u[2] = (unsigned int)sw0[1];   // kv 8hi+{4,5}
        pa.u[3] = (unsigned int)sw1[1];   // kv 8hi+{6,7}
        #pragma unroll
        for (int db = 0; db < 4; ++db){
          const int vrow = db * 32 + l31;
          const int vsl  = (kc * 2 + hi) ^ (vrow & 7);
          bf16x8 vf = *reinterpret_cast<const bf16x8*>(&Vs[vrow * 64 + vsl * 8]);
          o[db] = __builtin_amdgcn_mfma_f32_32x32x16_bf16(pa.v, vf, o[db], 0, 0, 0);
        }
      }
      __builtin_amdgcn_s_setprio(0);
    }
    __syncthreads();   // all reads done before next tile's DMA overwrites
  }

  if (nc == 1){
    // ---- final (Q<=2): O /= l; write AO in (B,T,C) bf16 ----
    float inv = 1.0f / lrun;                 // this lane's q = qw + l31
    #pragma unroll
    for (int r = 0; r < 16; ++r){
      const int crow = (r & 3) + 8 * (r >> 2) + 4 * hi;
      float ir = __shfl(inv, crow, 32);
      #pragma unroll
      for (int db = 0; db < 4; ++db)
        AO[((size_t)b * T_SEQ + qw + crow) * CDIM + h * HD + db * 32 + l31] =
            f2bf(o[db][r] * ir);
    }
  } else {
    // ---- partial: unnormalized O (bf16) + m,l per row (m in log2 domain) ----
    const int slot = bh * 46 + cumc(Q) + c;
    unsigned short* OpW = Op + (size_t)slot * 128 * 128;
    #pragma unroll
    for (int r = 0; r < 16; ++r){
      const int row = wave * 32 + (r & 3) + 8 * (r >> 2) + 4 * hi;
      #pragma unroll
      for (int db = 0; db < 4; ++db)
        OpW[row * 128 + db * 32 + l31] = f2bf(o[db][r]);
    }
    if (hi == 0){
      Mp[(size_t)slot * 128 + wave * 32 + l31] = mrun;
      Lp[(size_t)slot * 128 + wave * 32 + l31] = lrun;
    }
  }
}

// ---------------- combine partials for q-blocks with nc>=2 (Q=3..15) ----------------
__global__ __launch_bounds__(256) void attn_combine(
    const unsigned short* __restrict__ Op, const float* __restrict__ Mp,
    const float* __restrict__ Lp, unsigned short* __restrict__ AO)
{
  const int Q  = 3 + blockIdx.x;            // 3..15
  const int bh = blockIdx.y;
  const int b = bh / NH, h = bh % NH;
  const int nc = ncq(Q);
  const int slot0 = bh * 46 + cumc(Q);
  #pragma unroll
  for (int u = 0; u < 16; ++u){
    int unit = threadIdx.x + u * 256;       // 128 rows x 32 4-col groups
    int r = unit >> 5, d4 = unit & 31;
    float m = -__builtin_inff();
    for (int cc = 0; cc < nc; ++cc)
      m = fmaxf(m, Mp[(size_t)(slot0 + cc) * 128 + r]);
    float l = 0.f;
    float a0 = 0.f, a1 = 0.f, a2 = 0.f, a3 = 0.f;
    for (int cc = 0; cc < nc; ++cc){
      float w = __builtin_amdgcn_exp2f(Mp[(size_t)(slot0 + cc) * 128 + r] - m);
      l += w * Lp[(size_t)(slot0 + cc) * 128 + r];
      const ushort4 v = *reinterpret_cast<const ushort4*>(
          &Op[((size_t)(slot0 + cc) * 128 + r) * 128 + d4 * 4]);
      a0 += w * bf2f(v.x); a1 += w * bf2f(v.y);
      a2 += w * bf2f(v.z); a3 += w * bf2f(v.w);
    }
    float inv = 1.0f / l;
    ushort4 ov;
    ov.x = f2bf(a0 * inv); ov.y = f2bf(a1 * inv);
    ov.z = f2bf(a2 * inv); ov.w = f2bf(a3 * inv);
    *reinterpret_cast<ushort4*>(
        &AO[((size_t)b * T_SEQ + Q * 128 + r) * CDIM + h * HD + d4 * 4]) = ov;
  }
}

// ---------------- launch ----------------
extern "C" void kernel_launch(void* const* d_in, const int* in_sizes, int n_in,
                              void* d_out, int out_size, void* d_ws, size_t ws_size,
                              hipStream_t stream)
{
  (void)in_sizes; (void)n_in; (void)out_size; (void)ws_size;
  const float* x    = (const float*)d_in[0];
  const float* cosp = (const float*)d_in[1];
  const float* sinp = (const float*)d_in[2];
  const float* Wq   = (const float*)d_in[3];
  const float* Wk   = (const float*)d_in[4];
  const float* Wv   = (const float*)d_in[5];
  const float* Wo   = (const float*)d_in[6];
  float* out = (float*)d_out;

  // workspace layout: bf16 region then partials (~120 MB)
  unsigned short* xb    = (unsigned short*)d_ws;
  unsigned short* Wqkvb = xb    + (size_t)MROWS * CDIM;
  unsigned short* Wob   = Wqkvb + (size_t)NQKV * CDIM;
  unsigned short* QKVb  = Wob   + (size_t)CDIM * CDIM;
  unsigned short* Vtb   = QKVb  + (size_t)MROWS * NQKV;
  unsigned short* AO    = Vtb   + (size_t)MROWS * CDIM;
  unsigned short* Op    = AO    + (size_t)MROWS * CDIM;
  float* Mp = (float*)(Op + (size_t)NSLOT * 128 * 128);
  float* Lp = Mp + (size_t)NSLOT * 128;

  int n4x = MROWS * CDIM / 4;
  cvt_f32_bf16<<<(n4x + 255) / 256, 256, 0, stream>>>(x, xb, n4x);
  cvt_w4<<<dim3(CDIM * CDIM / 4 / 256, 4), 256, 0, stream>>>(Wq, Wk, Wv, Wo, Wqkvb);

  // fused QKV projection + RoPE/RMSNorm(+Q-prescale) + V-transpose epilogue
  gemm_bt<1><<<dim3(MROWS / 128, NQKV / 128), 256, 0, stream>>>(
      xb, Wqkvb, QKVb, MROWS, NQKV, CDIM, cosp, sinp, Vtb);
  // causal flash attention, balanced split-KV -> AO (+partials)
  attn_fwd<<<NSLOT, 256, 0, stream>>>(QKVb, Vtb, AO, Op, Mp, Lp);
  attn_combine<<<dim3(13, 24), 256, 0, stream>>>(Op, Mp, Lp, AO);
  // output projection -> f32 d_out
  gemm_bt<0><<<dim3(MROWS / 128, CDIM / 128), 256, 0, stream>>>(
      AO, Wob, out, MROWS, CDIM, CDIM, nullptr, nullptr, nullptr);
}

// Round 19
// 210.387 us; speedup vs baseline: 1.7236x; 1.7236x over previous
//
#include <hip/hip_runtime.h>

#define T_SEQ 2048
#define NH    6
#define HD    128
#define CDIM  768
#define NQKV  2304
#define MROWS 8192   // B*T = 4*2048
#define NSLOT 1104   // 46 chunks per (b,h) * 24
// 1/sqrt(128) * log2(e): folded into Q during gemm1 epilogue
#define QSCL  0.12754011021989615f

typedef __attribute__((ext_vector_type(8)))  short bf16x8;
typedef __attribute__((ext_vector_type(4)))  float f32x4;
typedef __attribute__((ext_vector_type(16))) float f32x16;
typedef __attribute__((ext_vector_type(2)))  int   i32x2;

__device__ __forceinline__ unsigned short f2bf(float f){
  unsigned int u = __builtin_bit_cast(unsigned int, f);
  u += 0x7fffu + ((u >> 16) & 1u);          // round-to-nearest-even
  return (unsigned short)(u >> 16);
}
__device__ __forceinline__ float bf2f(unsigned short h){
  unsigned int u = ((unsigned int)h) << 16;
  return __builtin_bit_cast(float, u);
}
// raw v_exp_f32: computes 2^x in one instruction (no libm slow path)
__device__ __forceinline__ float ex2(float x){
  return __builtin_amdgcn_exp2f(x);
}
// pack 2 f32 -> 2 bf16 in one instr
__device__ __forceinline__ unsigned int cvtpk(float lo, float hi){
  unsigned int r;
  asm("v_cvt_pk_bf16_f32 %0, %1, %2" : "=v"(r) : "v"(lo), "v"(hi));
  return r;
}

// async global->LDS, 16B per lane; LDS dest is wave-uniform base + lane*16
__device__ __forceinline__ void gload_lds16(const void* g, void* l){
  __builtin_amdgcn_global_load_lds(
      (const __attribute__((address_space(1))) unsigned int*)g,
      (__attribute__((address_space(3))) unsigned int*)l, 16, 0, 0);
}

// chunking: q-block Q (QBLK=128) has 2Q+2 tiles of 64; nc = ceil((2Q+2)/7)
__device__ __forceinline__ int ncq(int Q){
  return Q < 3 ? 1 : Q < 7 ? 2 : Q < 10 ? 3 : Q < 14 ? 4 : 5;
}
// chunks before q-block Q
__device__ __forceinline__ int cumc(int Q){
  return Q < 4 ? Q : Q < 8 ? 3 + 2*(Q-3) : Q < 11 ? 11 + 3*(Q-7)
       : Q < 15 ? 20 + 4*(Q-10) : 36 + 5*(Q-14);
}

// ---------------- f32 -> bf16 conversion (vectorized) ----------------
__global__ __launch_bounds__(256) void cvt_f32_bf16(
    const float* __restrict__ in, unsigned short* __restrict__ out, int n4){
  int i = blockIdx.x * 256 + threadIdx.x;
  if (i >= n4) return;
  float4 v = reinterpret_cast<const float4*>(in)[i];
  ushort4 o;
  o.x = f2bf(v.x); o.y = f2bf(v.y); o.z = f2bf(v.z); o.w = f2bf(v.w);
  reinterpret_cast<ushort4*>(out)[i] = o;
}

// 4 weight matrices (each CDIM*CDIM f32) -> contiguous bf16 (Wqkv then Wo)
__global__ __launch_bounds__(256) void cvt_w4(
    const float* __restrict__ w0, const float* __restrict__ w1,
    const float* __restrict__ w2, const float* __restrict__ w3,
    unsigned short* __restrict__ out){
  const int which = blockIdx.y;
  const float* src = which == 0 ? w0 : which == 1 ? w1 : which == 2 ? w2 : w3;
  int i = blockIdx.x * 256 + threadIdx.x;           // in float4 units
  float4 v = reinterpret_cast<const float4*>(src)[i];
  ushort4 o;
  o.x = f2bf(v.x); o.y = f2bf(v.y); o.z = f2bf(v.z); o.w = f2bf(v.w);
  reinterpret_cast<ushort4*>(out + (size_t)which * CDIM * CDIM)[i] = o;
}

// ---------------- GEMM: C = A(MxK,bf16) * B(NxK,bf16)^T ----------------
// 128x128 tile, BK=64, global_load_lds(16B) into linear LDS, XOR slot-swizzle
// both-sides. Waves own 32 ROWS x 128 cols (acc[2][8]); EPI=1 fuses
// RoPE+RMSNorm for q/k col-tiles of QKV (Q additionally pre-scaled by
// 1/sqrt(128)*log2e so attention softmax runs in exp2 domain) and
// TRANSPOSES V col-tiles into Vt via LDS bounce.
template<int EPI>
__global__ __launch_bounds__(256) void gemm_bt(
    const unsigned short* __restrict__ A,
    const unsigned short* __restrict__ B,
    void* __restrict__ Cv, int M, int N, int K,
    const float* __restrict__ cosp, const float* __restrict__ sinp,
    unsigned short* __restrict__ Vt)
{
  __shared__ unsigned short sh[128 * 128];  // As = sh[0:8192), Bs = sh[8192:)
  unsigned short* As = sh;
  unsigned short* Bs = sh + 128 * 64;
  const int tid  = threadIdx.x;
  const int lane = tid & 63;
  const int wave = tid >> 6;
  const int lr = lane & 15, lg = lane >> 4;
  const int srow = lane >> 3;               // staging row within 8-row seg
  const int sslot = (lane & 7) ^ (lane >> 3);  // pre-swizzled global slot
  // XCD-aware swizzle; within an XCD, col-tiles vary fastest (A-panel reuse)
  const int gx = gridDim.x, gy = gridDim.y, nwg = gx * gy;
  const int flat = blockIdx.y * gx + blockIdx.x;
  const int nf = (flat & 7) * (nwg >> 3) + (flat >> 3);
  const int row0 = (nf / gy) * 128, col0 = (nf % gy) * 128;
  const int wrow = wave * 32;               // wave's row base within tile

  f32x4 acc[2][8];
  const f32x4 z = {0.f, 0.f, 0.f, 0.f};
  #pragma unroll
  for (int i = 0; i < 2; ++i)
    #pragma unroll
    for (int j = 0; j < 8; ++j) acc[i][j] = z;

  for (int k0 = 0; k0 < K; k0 += 64){
    #pragma unroll
    for (int i = 0; i < 4; ++i){
      int seg = wave * 4 + i;                 // 8 rows per 1KB segment
      int r = seg * 8 + srow;
      gload_lds16(&A[(size_t)(row0 + r) * K + k0 + sslot * 8], &As[seg * 512]);
      gload_lds16(&B[(size_t)(col0 + r) * K + k0 + sslot * 8], &Bs[seg * 512]);
    }
    __syncthreads();
    #pragma unroll
    for (int kk = 0; kk < 64; kk += 32){
      bf16x8 af[2], bfr[8];
      #pragma unroll
      for (int mi = 0; mi < 2; ++mi)
        af[mi] = *reinterpret_cast<const bf16x8*>(
            &As[(wrow + mi*16 + lr) * 64 + ((((kk>>3) + lg) ^ (lr & 7)) * 8)]);
      #pragma unroll
      for (int ni = 0; ni < 8; ++ni)
        bfr[ni] = *reinterpret_cast<const bf16x8*>(
            &Bs[(ni*16 + lr) * 64 + ((((kk>>3) + lg) ^ (lr & 7)) * 8)]);
      #pragma unroll
      for (int mi = 0; mi < 2; ++mi)
        #pragma unroll
        for (int ni = 0; ni < 8; ++ni)
          acc[mi][ni] = __builtin_amdgcn_mfma_f32_16x16x32_bf16(af[mi], bfr[ni], acc[mi][ni], 0, 0, 0);
    }
    __syncthreads();
  }

  if (EPI == 0){
    float* Cf = reinterpret_cast<float*>(Cv);
    #pragma unroll
    for (int mi = 0; mi < 2; ++mi)
      #pragma unroll
      for (int ni = 0; ni < 8; ++ni)
        #pragma unroll
        for (int r = 0; r < 4; ++r)
          Cf[(size_t)(row0 + wrow + mi*16 + lg*4 + r) * N + col0 + ni*16 + lr] = acc[mi][ni][r];
  } else {
    unsigned short* Cb = reinterpret_cast<unsigned short*>(Cv);
    const int ct = col0 >> 7;               // 0..17
    if (ct >= 12){
      // V tile: transpose via LDS bounce -> Vt[(b,h)][d][t]
      const int hh = ct - 12;
      const int b2 = row0 >> 11, t0 = row0 & (T_SEQ - 1);
      #pragma unroll
      for (int mi = 0; mi < 2; ++mi)
        #pragma unroll
        for (int ni = 0; ni < 8; ++ni)
          #pragma unroll
          for (int r = 0; r < 4; ++r){
            const int trow = wrow + mi*16 + lg*4 + r;
            const int col  = ni*16 + lr;
            sh[trow * 128 + (col ^ ((trow & 7) << 4))] = f2bf(acc[mi][ni][r]);
          }
      __syncthreads();
      const int dd = tid >> 1, tq = (tid & 1) * 64;
      unsigned short* dst =
          Vt + ((size_t)(b2 * NH + hh) * HD + dd) * T_SEQ + t0 + tq;
      #pragma unroll
      for (int j8 = 0; j8 < 8; ++j8){
        union { int4 v; unsigned short u[8]; } w;
        #pragma unroll
        for (int jj = 0; jj < 8; ++jj){
          const int tt = tq + j8 * 8 + jj;     // (tt & 7) == jj
          w.u[jj] = sh[tt * 128 + (dd ^ (jj << 4))];
        }
        *reinterpret_cast<int4*>(&dst[j8 * 8]) = w.v;
      }
    } else {
      // Q or K: RoPE (pairs d, d+64 = ni, ni+4) + RMSNorm over 128, then bf16
      // Q tiles (ct<6) additionally scaled by QSCL (softmax exp2-domain)
      const float post = (ct < 6) ? QSCL : 1.0f;
      #pragma unroll
      for (int mi = 0; mi < 2; ++mi){
        #pragma unroll
        for (int r = 0; r < 4; ++r){
          const int row = row0 + wrow + mi*16 + lg*4 + r;
          const int t = row & (T_SEQ - 1);
          float y1[4], y2[4], ssp = 0.f;
          #pragma unroll
          for (int ni = 0; ni < 4; ++ni){
            const int d = ni*16 + lr;
            float c = cosp[t * 64 + d];
            float s = sinp[t * 64 + d];
            float x1 = acc[mi][ni][r], x2 = acc[mi][ni+4][r];
            y1[ni] = x1 * c + x2 * s;
            y2[ni] = x2 * c - x1 * s;
            ssp += y1[ni]*y1[ni] + y2[ni]*y2[ni];
          }
          #pragma unroll
          for (int off = 1; off < 16; off <<= 1) ssp += __shfl_xor(ssp, off);
          const float inv = rsqrtf(ssp * (1.0f / 128.0f) + 1e-15f) * post;
          #pragma unroll
          for (int ni = 0; ni < 4; ++ni){
            const int d = ni*16 + lr;
            Cb[(size_t)row * N + col0 + d]      = f2bf(y1[ni] * inv);
            Cb[(size_t)row * N + col0 + d + 64] = f2bf(y2[ni] * inv);
          }
        }
      }
    }
  }
}

// ---------------- causal flash attention: 32x32 swapped-operand, balanced split-KV ----------------
// 4 waves x 32 q-rows (QBLK=128), KVBLK=64, chunks of <=7 tiles -> 1104 blocks.
// Q pre-scaled by 1/sqrt(128)*log2e -> softmax in exp2 domain via RAW
// v_exp_f32 (__builtin_amdgcn_exp2f): one transcendental, zero muls.
// T14 async-STAGE split staging. XCD-local heads (3 per XCD).
__global__ __launch_bounds__(256) void attn_fwd(
    const unsigned short* __restrict__ QKVb,   // rope'd Q,K in place
    const unsigned short* __restrict__ Vt,     // (B*H, D, T)
    unsigned short* __restrict__ AO,
    unsigned short* __restrict__ Op, float* __restrict__ Mp, float* __restrict__ Lp)
{
  __shared__ unsigned short Ks[64][136];    // K tile [kv][d]
  __shared__ unsigned short Vs[128][72];    // V^T tile [d][kv]
  const int tid = threadIdx.x;
  const int lane = tid & 63, wave = tid >> 6;
  const int l31 = lane & 31, hi = lane >> 5;

  // XCD-aware remap: 1104 blocks, 138/XCD = 3 heads' 46 chunks each
  const int flat = blockIdx.x;
  const int nf = (flat & 7) * 138 + (flat >> 3);
  const int bh = nf / 46;
  const int L = 45 - (nf % 46);              // big chunks first within XCD
  int Q, c;
  if (L < 3)      { Q = L; c = 0; }
  else if (L < 11){ int m = L - 3;  Q = 3 + (m >> 1);  c = m & 1; }
  else if (L < 20){ int m = L - 11; Q = 7 + m / 3;     c = m % 3; }
  else if (L < 36){ int m = L - 20; Q = 10 + (m >> 2); c = m & 3; }
  else            { int m = L - 36; Q = 14 + m / 5;    c = m % 5; }
  const int nc = ncq(Q);
  const int tiles = 2 * Q + 2;
  const int base = tiles / nc, rem = tiles % nc;
  const int tbeg = c * base + (c < rem ? c : rem);
  const int tend = tbeg + base + (c < rem ? 1 : 0);
  const int b = bh / NH, h = bh % NH;
  const int qw = Q * 128 + wave * 32;

  const unsigned short* Qp = QKVb + (size_t)(b * T_SEQ) * NQKV + h * HD;
  const unsigned short* Kp = QKVb + (size_t)(b * T_SEQ) * NQKV + CDIM + h * HD;
  const unsigned short* Vp = Vt + (size_t)bh * HD * T_SEQ;

  // staging coords (per thread): K: row kr (64 rows x 16 chunks), V: row vr
  const int kr = tid >> 4, kc4 = (tid & 15) * 8;    // K row, col chunk
  const int vr = tid >> 3, vc4 = (tid & 7) * 8;     // V d-row base

  // Q B-frags: B[k=8hi+j][n=l31] = Q[q=qw+l31][d=16c4+8hi+j]
  bf16x8 qf[8];
  #pragma unroll
  for (int c4 = 0; c4 < 8; ++c4)
    qf[c4] = *reinterpret_cast<const bf16x8*>(
        &Qp[(size_t)(qw + l31) * NQKV + c4 * 16 + hi * 8]);

  f32x16 o[4];
  #pragma unroll
  for (int db = 0; db < 4; ++db)
    #pragma unroll
    for (int r = 0; r < 16; ++r) o[db][r] = 0.f;
  float mrun = -__builtin_inff(), lrun = 0.f;   // mrun in log2 domain

  // prologue: load tile tbeg into registers
  int4 gk0, gk1, gk2, gk3, gv0, gv1, gv2, gv3;
  {
    const int kv0 = tbeg * 64;
    gk0 = *reinterpret_cast<const int4*>(&Kp[(size_t)(kv0 + kr)       * NQKV + kc4]);
    gk1 = *reinterpret_cast<const int4*>(&Kp[(size_t)(kv0 + kr + 16)  * NQKV + kc4]);
    gk2 = *reinterpret_cast<const int4*>(&Kp[(size_t)(kv0 + kr + 32)  * NQKV + kc4]);
    gk3 = *reinterpret_cast<const int4*>(&Kp[(size_t)(kv0 + kr + 48)  * NQKV + kc4]);
    gv0 = *reinterpret_cast<const int4*>(&Vp[(size_t)(vr)       * T_SEQ + kv0 + vc4]);
    gv1 = *reinterpret_cast<const int4*>(&Vp[(size_t)(vr + 32)  * T_SEQ + kv0 + vc4]);
    gv2 = *reinterpret_cast<const int4*>(&Vp[(size_t)(vr + 64)  * T_SEQ + kv0 + vc4]);
    gv3 = *reinterpret_cast<const int4*>(&Vp[(size_t)(vr + 96)  * T_SEQ + kv0 + vc4]);
  }

  for (int t = tbeg; t < tend; ++t){
    // ---- ds_write tile t from registers (vmcnt wait auto-inserted) ----
    *reinterpret_cast<int4*>(&Ks[kr][kc4])        = gk0;
    *reinterpret_cast<int4*>(&Ks[kr + 16][kc4])   = gk1;
    *reinterpret_cast<int4*>(&Ks[kr + 32][kc4])   = gk2;
    *reinterpret_cast<int4*>(&Ks[kr + 48][kc4])   = gk3;
    *reinterpret_cast<int4*>(&Vs[vr][vc4])        = gv0;
    *reinterpret_cast<int4*>(&Vs[vr + 32][vc4])   = gv1;
    *reinterpret_cast<int4*>(&Vs[vr + 64][vc4])   = gv2;
    *reinterpret_cast<int4*>(&Vs[vr + 96][vc4])   = gv3;
    __syncthreads();

    // ---- issue tile t+1 loads (latency hides under compute below) ----
    if (t + 1 < tend){
      const int kn = (t + 1) * 64;
      gk0 = *reinterpret_cast<const int4*>(&Kp[(size_t)(kn + kr)       * NQKV + kc4]);
      gk1 = *reinterpret_cast<const int4*>(&Kp[(size_t)(kn + kr + 16)  * NQKV + kc4]);
      gk2 = *reinterpret_cast<const int4*>(&Kp[(size_t)(kn + kr + 32)  * NQKV + kc4]);
      gk3 = *reinterpret_cast<const int4*>(&Kp[(size_t)(kn + kr + 48)  * NQKV + kc4]);
      gv0 = *reinterpret_cast<const int4*>(&Vp[(size_t)(vr)       * T_SEQ + kn + vc4]);
      gv1 = *reinterpret_cast<const int4*>(&Vp[(size_t)(vr + 32)  * T_SEQ + kn + vc4]);
      gv2 = *reinterpret_cast<const int4*>(&Vp[(size_t)(vr + 64)  * T_SEQ + kn + vc4]);
      gv3 = *reinterpret_cast<const int4*>(&Vp[(size_t)(vr + 96)  * T_SEQ + kn + vc4]);
    }

    const int kv0 = t * 64;
    if (kv0 <= qw + 31){                     // tile has unmasked work for this wave
      // ---- S^T = K Q^T (Q pre-scaled): lane holds S[kv][q=qw+l31] ----
      f32x16 s[2];
      #pragma unroll
      for (int r = 0; r < 16; ++r){ s[0][r] = 0.f; s[1][r] = 0.f; }
      __builtin_amdgcn_s_setprio(1);
      #pragma unroll
      for (int c4 = 0; c4 < 8; ++c4){
        bf16x8 k0 = *reinterpret_cast<const bf16x8*>(&Ks[l31][c4 * 16 + hi * 8]);
        bf16x8 k1 = *reinterpret_cast<const bf16x8*>(&Ks[32 + l31][c4 * 16 + hi * 8]);
        s[0] = __builtin_amdgcn_mfma_f32_32x32x16_bf16(k0, qf[c4], s[0], 0, 0, 0);
        s[1] = __builtin_amdgcn_mfma_f32_32x32x16_bf16(k1, qf[c4], s[1], 0, 0, 0);
      }
      __builtin_amdgcn_s_setprio(0);

      // ---- causal mask (diagonal tiles only; interior: no scale work) ----
      const int qg = qw + l31;
      if (kv0 + 63 > qw){
        #pragma unroll
        for (int blk = 0; blk < 2; ++blk)
          #pragma unroll
          for (int r = 0; r < 16; ++r){
            int kg = kv0 + 32 * blk + (r & 3) + 8 * (r >> 2) + 4 * hi;
            s[blk][r] = (kg <= qg) ? s[blk][r] : -__builtin_inff();
          }
      }

      // ---- row max: tree over own 32 + 1 cross-half shuffle ----
      float t8[8];
      #pragma unroll
      for (int blk = 0; blk < 2; ++blk)
        #pragma unroll
        for (int j = 0; j < 4; ++j)
          t8[blk * 4 + j] = fmaxf(fmaxf(s[blk][4*j], s[blk][4*j+1]),
                                  fmaxf(s[blk][4*j+2], s[blk][4*j+3]));
      float pm = fmaxf(fmaxf(fmaxf(t8[0], t8[1]), fmaxf(t8[2], t8[3])),
                       fmaxf(fmaxf(t8[4], t8[5]), fmaxf(t8[6], t8[7])));
      pm = fmaxf(pm, __shfl_xor(pm, 32));

      // ---- deferred rescale (wave-uniform; exp2 domain, raw v_exp) ----
      if (__any(pm > mrun)){
        float mn = fmaxf(mrun, pm);
        float scf = (mrun == -__builtin_inff()) ? 0.f : ex2(mrun - mn);
        mrun = mn; lrun *= scf;
        #pragma unroll
        for (int r = 0; r < 16; ++r){
          float scr = __shfl(scf, (r & 3) + 8 * (r >> 2) + 4 * hi, 32);
          #pragma unroll
          for (int db = 0; db < 4; ++db) o[db][r] *= scr;
        }
      }

      // ---- exp2 (raw v_exp_f32) + row sum ----
      float a8[8];
      #pragma unroll
      for (int blk = 0; blk < 2; ++blk)
        #pragma unroll
        for (int j = 0; j < 4; ++j){
          float p0 = ex2(s[blk][4*j]   - mrun);
          float p1 = ex2(s[blk][4*j+1] - mrun);
          float p2 = ex2(s[blk][4*j+2] - mrun);
          float p3 = ex2(s[blk][4*j+3] - mrun);
          s[blk][4*j] = p0; s[blk][4*j+1] = p1; s[blk][4*j+2] = p2; s[blk][4*j+3] = p3;
          a8[blk * 4 + j] = (p0 + p1) + (p2 + p3);
        }
      float ls = ((a8[0] + a8[1]) + (a8[2] + a8[3])) + ((a8[4] + a8[5]) + (a8[6] + a8[7]));
      lrun += ls + __shfl_xor(ls, 32);

      // ---- O += P V : A-frags via cvt_pk + permlane32_swap ----
      __builtin_amdgcn_s_setprio(1);
      #pragma unroll
      for (int kc = 0; kc < 4; ++kc){
        const int blk = kc >> 1, base2 = (kc & 1) * 8;
        unsigned int a0 = cvtpk(s[blk][base2+0], s[blk][base2+1]);
        unsigned int b0 = cvtpk(s[blk][base2+4], s[blk][base2+5]);
        unsigned int a1 = cvtpk(s[blk][base2+2], s[blk][base2+3]);
        unsigned int b1 = cvtpk(s[blk][base2+6], s[blk][base2+7]);
        i32x2 sw0 = __builtin_amdgcn_permlane32_swap((int)a0, (int)b0, false, false);
        i32x2 sw1 = __builtin_amdgcn_permlane32_swap((int)a1, (int)b1, false, false);
        union { bf16x8 v; unsigned int u[4]; } pa;
        pa.u[0] = (unsigned int)sw0[0];   // kv 8hi+{0,1}
        pa.u[1] = (unsigned int)sw1[0];   // kv 8hi+{2,3}
        pa.u[2] = (unsigned int)sw0[1];   // kv 8hi+{4,5}
        pa.u[3] = (unsigned int)sw1[1];   // kv 8hi+{6,7}
        #pragma unroll
        for (int db = 0; db < 4; ++db){
          bf16x8 vf = *reinterpret_cast<const bf16x8*>(
              &Vs[db * 32 + l31][kc * 16 + hi * 8]);
          o[db] = __builtin_amdgcn_mfma_f32_32x32x16_bf16(pa.v, vf, o[db], 0, 0, 0);
        }
      }
      __builtin_amdgcn_s_setprio(0);
    }
    __syncthreads();   // Ks/Vs free for next tile's ds_writes
  }

  if (nc == 1){
    // ---- final (Q<=2): O /= l; write AO in (B,T,C) bf16 ----
    float inv = 1.0f / lrun;                 // this lane's q = qw + l31
    #pragma unroll
    for (int r = 0; r < 16; ++r){
      const int crow = (r & 3) + 8 * (r >> 2) + 4 * hi;
      float ir = __shfl(inv, crow, 32);
      #pragma unroll
      for (int db = 0; db < 4; ++db)
        AO[((size_t)b * T_SEQ + qw + crow) * CDIM + h * HD + db * 32 + l31] =
            f2bf(o[db][r] * ir);
    }
  } else {
    // ---- partial: unnormalized O (bf16) + m,l per row (m in log2 domain) ----
    const int slot = bh * 46 + cumc(Q) + c;
    unsigned short* OpW = Op + (size_t)slot * 128 * 128;
    #pragma unroll
    for (int r = 0; r < 16; ++r){
      const int row = wave * 32 + (r & 3) + 8 * (r >> 2) + 4 * hi;
      #pragma unroll
      for (int db = 0; db < 4; ++db)
        OpW[row * 128 + db * 32 + l31] = f2bf(o[db][r]);
    }
    if (hi == 0){
      Mp[(size_t)slot * 128 + wave * 32 + l31] = mrun;
      Lp[(size_t)slot * 128 + wave * 32 + l31] = lrun;
    }
  }
}

// ---------------- combine partials for q-blocks with nc>=2 (Q=3..15) ----------------
__global__ __launch_bounds__(256) void attn_combine(
    const unsigned short* __restrict__ Op, const float* __restrict__ Mp,
    const float* __restrict__ Lp, unsigned short* __restrict__ AO)
{
  const int Q  = 3 + blockIdx.x;            // 3..15
  const int bh = blockIdx.y;
  const int b = bh / NH, h = bh % NH;
  const int nc = ncq(Q);
  const int slot0 = bh * 46 + cumc(Q);
  #pragma unroll
  for (int u = 0; u < 16; ++u){
    int unit = threadIdx.x + u * 256;       // 128 rows x 32 4-col groups
    int r = unit >> 5, d4 = unit & 31;
    float m = -__builtin_inff();
    for (int cc = 0; cc < nc; ++cc)
      m = fmaxf(m, Mp[(size_t)(slot0 + cc) * 128 + r]);
    float l = 0.f;
    float a0 = 0.f, a1 = 0.f, a2 = 0.f, a3 = 0.f;
    for (int cc = 0; cc < nc; ++cc){
      float w = __builtin_amdgcn_exp2f(Mp[(size_t)(slot0 + cc) * 128 + r] - m);
      l += w * Lp[(size_t)(slot0 + cc) * 128 + r];
      const ushort4 v = *reinterpret_cast<const ushort4*>(
          &Op[((size_t)(slot0 + cc) * 128 + r) * 128 + d4 * 4]);
      a0 += w * bf2f(v.x); a1 += w * bf2f(v.y);
      a2 += w * bf2f(v.z); a3 += w * bf2f(v.w);
    }
    float inv = 1.0f / l;
    ushort4 ov;
    ov.x = f2bf(a0 * inv); ov.y = f2bf(a1 * inv);
    ov.z = f2bf(a2 * inv); ov.w = f2bf(a3 * inv);
    *reinterpret_cast<ushort4*>(
        &AO[((size_t)b * T_SEQ + Q * 128 + r) * CDIM + h * HD + d4 * 4]) = ov;
  }
}

// ---------------- launch ----------------
extern "C" void kernel_launch(void* const* d_in, const int* in_sizes, int n_in,
                              void* d_out, int out_size, void* d_ws, size_t ws_size,
                              hipStream_t stream)
{
  (void)in_sizes; (void)n_in; (void)out_size; (void)ws_size;
  const float* x    = (const float*)d_in[0];
  const float* cosp = (const float*)d_in[1];
  const float* sinp = (const float*)d_in[2];
  const float* Wq   = (const float*)d_in[3];
  const float* Wk   = (const float*)d_in[4];
  const float* Wv   = (const float*)d_in[5];
  const float* Wo   = (const float*)d_in[6];
  float* out = (float*)d_out;

  // workspace layout: bf16 region then partials (~120 MB)
  unsigned short* xb    = (unsigned short*)d_ws;
  unsigned short* Wqkvb = xb    + (size_t)MROWS * CDIM;
  unsigned short* Wob   = Wqkvb + (size_t)NQKV * CDIM;
  unsigned short* QKVb  = Wob   + (size_t)CDIM * CDIM;
  unsigned short* Vtb   = QKVb  + (size_t)MROWS * NQKV;
  unsigned short* AO    = Vtb   + (size_t)MROWS * CDIM;
  unsigned short* Op    = AO    + (size_t)MROWS * CDIM;
  float* Mp = (float*)(Op + (size_t)NSLOT * 128 * 128);
  float* Lp = Mp + (size_t)NSLOT * 128;

  int n4x = MROWS * CDIM / 4;
  cvt_f32_bf16<<<(n4x + 255) / 256, 256, 0, stream>>>(x, xb, n4x);
  cvt_w4<<<dim3(CDIM * CDIM / 4 / 256, 4), 256, 0, stream>>>(Wq, Wk, Wv, Wo, Wqkvb);

  // fused QKV projection + RoPE/RMSNorm(+Q-prescale) + V-transpose epilogue
  gemm_bt<1><<<dim3(MROWS / 128, NQKV / 128), 256, 0, stream>>>(
      xb, Wqkvb, QKVb, MROWS, NQKV, CDIM, cosp, sinp, Vtb);
  // causal flash attention, balanced split-KV -> AO (+partials)
  attn_fwd<<<NSLOT, 256, 0, stream>>>(QKVb, Vtb, AO, Op, Mp, Lp);
  attn_combine<<<dim3(13, 24), 256, 0, stream>>>(Op, Mp, Lp, AO);
  // output projection -> f32 d_out
  gemm_bt<0><<<dim3(MROWS / 128, CDIM / 128), 256, 0, stream>>>(
      AO, Wob, out, MROWS, CDIM, CDIM, nullptr, nullptr, nullptr);
}

// Round 20
// 207.931 us; speedup vs baseline: 1.7440x; 1.0118x over previous
//
#include <hip/hip_runtime.h>

#define T_SEQ 2048
#define NH    6
#define HD    128
#define CDIM  768
#define NQKV  2304
#define MROWS 8192   // B*T = 4*2048
#define NSLOT 1104   // 46 chunks per (b,h) * 24
// 1/sqrt(128) * log2(e): folded into Q during gemm1 epilogue
#define QSCL  0.12754011021989615f

typedef __attribute__((ext_vector_type(8)))  short bf16x8;
typedef __attribute__((ext_vector_type(4)))  float f32x4;
typedef __attribute__((ext_vector_type(16))) float f32x16;
typedef __attribute__((ext_vector_type(2)))  int   i32x2;

__device__ __forceinline__ unsigned short f2bf(float f){
  unsigned int u = __builtin_bit_cast(unsigned int, f);
  u += 0x7fffu + ((u >> 16) & 1u);          // round-to-nearest-even
  return (unsigned short)(u >> 16);
}
__device__ __forceinline__ float bf2f(unsigned short h){
  unsigned int u = ((unsigned int)h) << 16;
  return __builtin_bit_cast(float, u);
}
// raw v_exp_f32: computes 2^x in one instruction (no libm slow path)
__device__ __forceinline__ float ex2(float x){
  return __builtin_amdgcn_exp2f(x);
}
// pack 2 f32 -> 2 bf16 in one instr
__device__ __forceinline__ unsigned int cvtpk(float lo, float hi){
  unsigned int r;
  asm("v_cvt_pk_bf16_f32 %0, %1, %2" : "=v"(r) : "v"(lo), "v"(hi));
  return r;
}

// async global->LDS, 16B per lane; LDS dest is wave-uniform base + lane*16
__device__ __forceinline__ void gload_lds16(const void* g, void* l){
  __builtin_amdgcn_global_load_lds(
      (const __attribute__((address_space(1))) unsigned int*)g,
      (__attribute__((address_space(3))) unsigned int*)l, 16, 0, 0);
}

// chunking: q-block Q (QBLK=128) has 2Q+2 tiles of 64; nc = ceil((2Q+2)/7)
__device__ __forceinline__ int ncq(int Q){
  return Q < 3 ? 1 : Q < 7 ? 2 : Q < 10 ? 3 : Q < 14 ? 4 : 5;
}
// chunks before q-block Q
__device__ __forceinline__ int cumc(int Q){
  return Q < 4 ? Q : Q < 8 ? 3 + 2*(Q-3) : Q < 11 ? 11 + 3*(Q-7)
       : Q < 15 ? 20 + 4*(Q-10) : 36 + 5*(Q-14);
}

// ---------------- all f32->bf16 conversions in ONE launch ----------------
// blocks [0,6144): x (MROWS*CDIM); blocks [6144,8448): 4 weights (576 each)
__global__ __launch_bounds__(256) void cvt_all(
    const float* __restrict__ x,
    const float* __restrict__ w0, const float* __restrict__ w1,
    const float* __restrict__ w2, const float* __restrict__ w3,
    unsigned short* __restrict__ xb, unsigned short* __restrict__ wout){
  const int bid = blockIdx.x;
  const float* src;
  unsigned short* dst;
  int i;
  if (bid < 6144){
    src = x; dst = xb;
    i = bid * 256 + threadIdx.x;
  } else {
    const int wb = bid - 6144;
    const int which = wb / 576;
    src = which == 0 ? w0 : which == 1 ? w1 : which == 2 ? w2 : w3;
    dst = wout + (size_t)which * CDIM * CDIM;
    i = (wb % 576) * 256 + threadIdx.x;
  }
  float4 v = reinterpret_cast<const float4*>(src)[i];
  ushort4 o;
  o.x = f2bf(v.x); o.y = f2bf(v.y); o.z = f2bf(v.z); o.w = f2bf(v.w);
  reinterpret_cast<ushort4*>(dst)[i] = o;
}

// ---------------- GEMM: C = A(MxK,bf16) * B(NxK,bf16)^T ----------------
// 128x128 tile, BK=64, global_load_lds(16B) into linear LDS, XOR slot-swizzle
// both-sides. Waves own 32 ROWS x 128 cols (acc[2][8]); EPI=1 fuses
// RoPE+RMSNorm for q/k col-tiles of QKV (Q additionally pre-scaled by
// 1/sqrt(128)*log2e so attention softmax runs in exp2 domain) and
// TRANSPOSES V col-tiles into Vt via LDS bounce.
template<int EPI>
__global__ __launch_bounds__(256) void gemm_bt(
    const unsigned short* __restrict__ A,
    const unsigned short* __restrict__ B,
    void* __restrict__ Cv, int M, int N, int K,
    const float* __restrict__ cosp, const float* __restrict__ sinp,
    unsigned short* __restrict__ Vt)
{
  __shared__ unsigned short sh[128 * 128];  // As = sh[0:8192), Bs = sh[8192:)
  unsigned short* As = sh;
  unsigned short* Bs = sh + 128 * 64;
  const int tid  = threadIdx.x;
  const int lane = tid & 63;
  const int wave = tid >> 6;
  const int lr = lane & 15, lg = lane >> 4;
  const int srow = lane >> 3;               // staging row within 8-row seg
  const int sslot = (lane & 7) ^ (lane >> 3);  // pre-swizzled global slot
  // XCD-aware swizzle; within an XCD, col-tiles vary fastest (A-panel reuse)
  const int gx = gridDim.x, gy = gridDim.y, nwg = gx * gy;
  const int flat = blockIdx.y * gx + blockIdx.x;
  const int nf = (flat & 7) * (nwg >> 3) + (flat >> 3);
  const int row0 = (nf / gy) * 128, col0 = (nf % gy) * 128;
  const int wrow = wave * 32;               // wave's row base within tile

  f32x4 acc[2][8];
  const f32x4 z = {0.f, 0.f, 0.f, 0.f};
  #pragma unroll
  for (int i = 0; i < 2; ++i)
    #pragma unroll
    for (int j = 0; j < 8; ++j) acc[i][j] = z;

  for (int k0 = 0; k0 < K; k0 += 64){
    #pragma unroll
    for (int i = 0; i < 4; ++i){
      int seg = wave * 4 + i;                 // 8 rows per 1KB segment
      int r = seg * 8 + srow;
      gload_lds16(&A[(size_t)(row0 + r) * K + k0 + sslot * 8], &As[seg * 512]);
      gload_lds16(&B[(size_t)(col0 + r) * K + k0 + sslot * 8], &Bs[seg * 512]);
    }
    __syncthreads();
    #pragma unroll
    for (int kk = 0; kk < 64; kk += 32){
      bf16x8 af[2], bfr[8];
      #pragma unroll
      for (int mi = 0; mi < 2; ++mi)
        af[mi] = *reinterpret_cast<const bf16x8*>(
            &As[(wrow + mi*16 + lr) * 64 + ((((kk>>3) + lg) ^ (lr & 7)) * 8)]);
      #pragma unroll
      for (int ni = 0; ni < 8; ++ni)
        bfr[ni] = *reinterpret_cast<const bf16x8*>(
            &Bs[(ni*16 + lr) * 64 + ((((kk>>3) + lg) ^ (lr & 7)) * 8)]);
      #pragma unroll
      for (int mi = 0; mi < 2; ++mi)
        #pragma unroll
        for (int ni = 0; ni < 8; ++ni)
          acc[mi][ni] = __builtin_amdgcn_mfma_f32_16x16x32_bf16(af[mi], bfr[ni], acc[mi][ni], 0, 0, 0);
    }
    __syncthreads();
  }

  if (EPI == 0){
    float* Cf = reinterpret_cast<float*>(Cv);
    #pragma unroll
    for (int mi = 0; mi < 2; ++mi)
      #pragma unroll
      for (int ni = 0; ni < 8; ++ni)
        #pragma unroll
        for (int r = 0; r < 4; ++r)
          Cf[(size_t)(row0 + wrow + mi*16 + lg*4 + r) * N + col0 + ni*16 + lr] = acc[mi][ni][r];
  } else {
    unsigned short* Cb = reinterpret_cast<unsigned short*>(Cv);
    const int ct = col0 >> 7;               // 0..17
    if (ct >= 12){
      // V tile: transpose via LDS bounce -> Vt[(b,h)][d][t]
      const int hh = ct - 12;
      const int b2 = row0 >> 11, t0 = row0 & (T_SEQ - 1);
      #pragma unroll
      for (int mi = 0; mi < 2; ++mi)
        #pragma unroll
        for (int ni = 0; ni < 8; ++ni)
          #pragma unroll
          for (int r = 0; r < 4; ++r){
            const int trow = wrow + mi*16 + lg*4 + r;
            const int col  = ni*16 + lr;
            sh[trow * 128 + (col ^ ((trow & 7) << 4))] = f2bf(acc[mi][ni][r]);
          }
      __syncthreads();
      const int dd = tid >> 1, tq = (tid & 1) * 64;
      unsigned short* dst =
          Vt + ((size_t)(b2 * NH + hh) * HD + dd) * T_SEQ + t0 + tq;
      #pragma unroll
      for (int j8 = 0; j8 < 8; ++j8){
        union { int4 v; unsigned short u[8]; } w;
        #pragma unroll
        for (int jj = 0; jj < 8; ++jj){
          const int tt = tq + j8 * 8 + jj;     // (tt & 7) == jj
          w.u[jj] = sh[tt * 128 + (dd ^ (jj << 4))];
        }
        *reinterpret_cast<int4*>(&dst[j8 * 8]) = w.v;
      }
    } else {
      // Q or K: RoPE (pairs d, d+64 = ni, ni+4) + RMSNorm over 128, then bf16
      // Q tiles (ct<6) additionally scaled by QSCL (softmax exp2-domain)
      const float post = (ct < 6) ? QSCL : 1.0f;
      #pragma unroll
      for (int mi = 0; mi < 2; ++mi){
        #pragma unroll
        for (int r = 0; r < 4; ++r){
          const int row = row0 + wrow + mi*16 + lg*4 + r;
          const int t = row & (T_SEQ - 1);
          float y1[4], y2[4], ssp = 0.f;
          #pragma unroll
          for (int ni = 0; ni < 4; ++ni){
            const int d = ni*16 + lr;
            float c = cosp[t * 64 + d];
            float s = sinp[t * 64 + d];
            float x1 = acc[mi][ni][r], x2 = acc[mi][ni+4][r];
            y1[ni] = x1 * c + x2 * s;
            y2[ni] = x2 * c - x1 * s;
            ssp += y1[ni]*y1[ni] + y2[ni]*y2[ni];
          }
          #pragma unroll
          for (int off = 1; off < 16; off <<= 1) ssp += __shfl_xor(ssp, off);
          const float inv = rsqrtf(ssp * (1.0f / 128.0f) + 1e-15f) * post;
          #pragma unroll
          for (int ni = 0; ni < 4; ++ni){
            const int d = ni*16 + lr;
            Cb[(size_t)row * N + col0 + d]      = f2bf(y1[ni] * inv);
            Cb[(size_t)row * N + col0 + d + 64] = f2bf(y2[ni] * inv);
          }
        }
      }
    }
  }
}

// ---------------- causal flash attention: 32x32 swapped-operand, balanced split-KV ----------------
// 4 waves x 32 q-rows (QBLK=128), KVBLK=64, chunks of <=7 tiles -> 1104 blocks.
// Q pre-scaled by 1/sqrt(128)*log2e -> softmax in exp2 domain via RAW
// v_exp_f32 (__builtin_amdgcn_exp2f): one transcendental, zero muls.
// T14 async-STAGE split staging. XCD-local heads (3 per XCD).
__global__ __launch_bounds__(256) void attn_fwd(
    const unsigned short* __restrict__ QKVb,   // rope'd Q,K in place
    const unsigned short* __restrict__ Vt,     // (B*H, D, T)
    unsigned short* __restrict__ AO,
    unsigned short* __restrict__ Op, float* __restrict__ Mp, float* __restrict__ Lp)
{
  __shared__ unsigned short Ks[64][136];    // K tile [kv][d]
  __shared__ unsigned short Vs[128][72];    // V^T tile [d][kv]
  const int tid = threadIdx.x;
  const int lane = tid & 63, wave = tid >> 6;
  const int l31 = lane & 31, hi = lane >> 5;

  // XCD-aware remap: 1104 blocks, 138/XCD = 3 heads' 46 chunks each
  const int flat = blockIdx.x;
  const int nf = (flat & 7) * 138 + (flat >> 3);
  const int bh = nf / 46;
  const int L = 45 - (nf % 46);              // big chunks first within XCD
  int Q, c;
  if (L < 3)      { Q = L; c = 0; }
  else if (L < 11){ int m = L - 3;  Q = 3 + (m >> 1);  c = m & 1; }
  else if (L < 20){ int m = L - 11; Q = 7 + m / 3;     c = m % 3; }
  else if (L < 36){ int m = L - 20; Q = 10 + (m >> 2); c = m & 3; }
  else            { int m = L - 36; Q = 14 + m / 5;    c = m % 5; }
  const int nc = ncq(Q);
  const int tiles = 2 * Q + 2;
  const int base = tiles / nc, rem = tiles % nc;
  const int tbeg = c * base + (c < rem ? c : rem);
  const int tend = tbeg + base + (c < rem ? 1 : 0);
  const int b = bh / NH, h = bh % NH;
  const int qw = Q * 128 + wave * 32;

  const unsigned short* Qp = QKVb + (size_t)(b * T_SEQ) * NQKV + h * HD;
  const unsigned short* Kp = QKVb + (size_t)(b * T_SEQ) * NQKV + CDIM + h * HD;
  const unsigned short* Vp = Vt + (size_t)bh * HD * T_SEQ;

  // staging coords (per thread): K: row kr (64 rows x 16 chunks), V: row vr
  const int kr = tid >> 4, kc4 = (tid & 15) * 8;    // K row, col chunk
  const int vr = tid >> 3, vc4 = (tid & 7) * 8;     // V d-row base

  // Q B-frags: B[k=8hi+j][n=l31] = Q[q=qw+l31][d=16c4+8hi+j]
  bf16x8 qf[8];
  #pragma unroll
  for (int c4 = 0; c4 < 8; ++c4)
    qf[c4] = *reinterpret_cast<const bf16x8*>(
        &Qp[(size_t)(qw + l31) * NQKV + c4 * 16 + hi * 8]);

  f32x16 o[4];
  #pragma unroll
  for (int db = 0; db < 4; ++db)
    #pragma unroll
    for (int r = 0; r < 16; ++r) o[db][r] = 0.f;
  float mrun = -__builtin_inff(), lrun = 0.f;   // mrun in log2 domain

  // prologue: load tile tbeg into registers
  int4 gk0, gk1, gk2, gk3, gv0, gv1, gv2, gv3;
  {
    const int kv0 = tbeg * 64;
    gk0 = *reinterpret_cast<const int4*>(&Kp[(size_t)(kv0 + kr)       * NQKV + kc4]);
    gk1 = *reinterpret_cast<const int4*>(&Kp[(size_t)(kv0 + kr + 16)  * NQKV + kc4]);
    gk2 = *reinterpret_cast<const int4*>(&Kp[(size_t)(kv0 + kr + 32)  * NQKV + kc4]);
    gk3 = *reinterpret_cast<const int4*>(&Kp[(size_t)(kv0 + kr + 48)  * NQKV + kc4]);
    gv0 = *reinterpret_cast<const int4*>(&Vp[(size_t)(vr)       * T_SEQ + kv0 + vc4]);
    gv1 = *reinterpret_cast<const int4*>(&Vp[(size_t)(vr + 32)  * T_SEQ + kv0 + vc4]);
    gv2 = *reinterpret_cast<const int4*>(&Vp[(size_t)(vr + 64)  * T_SEQ + kv0 + vc4]);
    gv3 = *reinterpret_cast<const int4*>(&Vp[(size_t)(vr + 96)  * T_SEQ + kv0 + vc4]);
  }

  for (int t = tbeg; t < tend; ++t){
    // ---- ds_write tile t from registers (vmcnt wait auto-inserted) ----
    *reinterpret_cast<int4*>(&Ks[kr][kc4])        = gk0;
    *reinterpret_cast<int4*>(&Ks[kr + 16][kc4])   = gk1;
    *reinterpret_cast<int4*>(&Ks[kr + 32][kc4])   = gk2;
    *reinterpret_cast<int4*>(&Ks[kr + 48][kc4])   = gk3;
    *reinterpret_cast<int4*>(&Vs[vr][vc4])        = gv0;
    *reinterpret_cast<int4*>(&Vs[vr + 32][vc4])   = gv1;
    *reinterpret_cast<int4*>(&Vs[vr + 64][vc4])   = gv2;
    *reinterpret_cast<int4*>(&Vs[vr + 96][vc4])   = gv3;
    __syncthreads();

    // ---- issue tile t+1 loads (latency hides under compute below) ----
    if (t + 1 < tend){
      const int kn = (t + 1) * 64;
      gk0 = *reinterpret_cast<const int4*>(&Kp[(size_t)(kn + kr)       * NQKV + kc4]);
      gk1 = *reinterpret_cast<const int4*>(&Kp[(size_t)(kn + kr + 16)  * NQKV + kc4]);
      gk2 = *reinterpret_cast<const int4*>(&Kp[(size_t)(kn + kr + 32)  * NQKV + kc4]);
      gk3 = *reinterpret_cast<const int4*>(&Kp[(size_t)(kn + kr + 48)  * NQKV + kc4]);
      gv0 = *reinterpret_cast<const int4*>(&Vp[(size_t)(vr)       * T_SEQ + kn + vc4]);
      gv1 = *reinterpret_cast<const int4*>(&Vp[(size_t)(vr + 32)  * T_SEQ + kn + vc4]);
      gv2 = *reinterpret_cast<const int4*>(&Vp[(size_t)(vr + 64)  * T_SEQ + kn + vc4]);
      gv3 = *reinterpret_cast<const int4*>(&Vp[(size_t)(vr + 96)  * T_SEQ + kn + vc4]);
    }

    const int kv0 = t * 64;
    if (kv0 <= qw + 31){                     // tile has unmasked work for this wave
      // ---- S^T = K Q^T (Q pre-scaled): lane holds S[kv][q=qw+l31] ----
      f32x16 s[2];
      #pragma unroll
      for (int r = 0; r < 16; ++r){ s[0][r] = 0.f; s[1][r] = 0.f; }
      __builtin_amdgcn_s_setprio(1);
      #pragma unroll
      for (int c4 = 0; c4 < 8; ++c4){
        bf16x8 k0 = *reinterpret_cast<const bf16x8*>(&Ks[l31][c4 * 16 + hi * 8]);
        bf16x8 k1 = *reinterpret_cast<const bf16x8*>(&Ks[32 + l31][c4 * 16 + hi * 8]);
        s[0] = __builtin_amdgcn_mfma_f32_32x32x16_bf16(k0, qf[c4], s[0], 0, 0, 0);
        s[1] = __builtin_amdgcn_mfma_f32_32x32x16_bf16(k1, qf[c4], s[1], 0, 0, 0);
      }
      __builtin_amdgcn_s_setprio(0);

      // ---- causal mask (diagonal tiles only; interior: no scale work) ----
      const int qg = qw + l31;
      if (kv0 + 63 > qw){
        #pragma unroll
        for (int blk = 0; blk < 2; ++blk)
          #pragma unroll
          for (int r = 0; r < 16; ++r){
            int kg = kv0 + 32 * blk + (r & 3) + 8 * (r >> 2) + 4 * hi;
            s[blk][r] = (kg <= qg) ? s[blk][r] : -__builtin_inff();
          }
      }

      // ---- row max: tree over own 32 + 1 cross-half shuffle ----
      float t8[8];
      #pragma unroll
      for (int blk = 0; blk < 2; ++blk)
        #pragma unroll
        for (int j = 0; j < 4; ++j)
          t8[blk * 4 + j] = fmaxf(fmaxf(s[blk][4*j], s[blk][4*j+1]),
                                  fmaxf(s[blk][4*j+2], s[blk][4*j+3]));
      float pm = fmaxf(fmaxf(fmaxf(t8[0], t8[1]), fmaxf(t8[2], t8[3])),
                       fmaxf(fmaxf(t8[4], t8[5]), fmaxf(t8[6], t8[7])));
      pm = fmaxf(pm, __shfl_xor(pm, 32));

      // ---- deferred rescale (wave-uniform; exp2 domain, raw v_exp) ----
      if (__any(pm > mrun)){
        float mn = fmaxf(mrun, pm);
        float scf = (mrun == -__builtin_inff()) ? 0.f : ex2(mrun - mn);
        mrun = mn; lrun *= scf;
        #pragma unroll
        for (int r = 0; r < 16; ++r){
          float scr = __shfl(scf, (r & 3) + 8 * (r >> 2) + 4 * hi, 32);
          #pragma unroll
          for (int db = 0; db < 4; ++db) o[db][r] *= scr;
        }
      }

      // ---- exp2 (raw v_exp_f32) + row sum ----
      float a8[8];
      #pragma unroll
      for (int blk = 0; blk < 2; ++blk)
        #pragma unroll
        for (int j = 0; j < 4; ++j){
          float p0 = ex2(s[blk][4*j]   - mrun);
          float p1 = ex2(s[blk][4*j+1] - mrun);
          float p2 = ex2(s[blk][4*j+2] - mrun);
          float p3 = ex2(s[blk][4*j+3] - mrun);
          s[blk][4*j] = p0; s[blk][4*j+1] = p1; s[blk][4*j+2] = p2; s[blk][4*j+3] = p3;
          a8[blk * 4 + j] = (p0 + p1) + (p2 + p3);
        }
      float ls = ((a8[0] + a8[1]) + (a8[2] + a8[3])) + ((a8[4] + a8[5]) + (a8[6] + a8[7]));
      lrun += ls + __shfl_xor(ls, 32);

      // ---- O += P V : A-frags via cvt_pk + permlane32_swap ----
      __builtin_amdgcn_s_setprio(1);
      #pragma unroll
      for (int kc = 0; kc < 4; ++kc){
        const int blk = kc >> 1, base2 = (kc & 1) * 8;
        unsigned int a0 = cvtpk(s[blk][base2+0], s[blk][base2+1]);
        unsigned int b0 = cvtpk(s[blk][base2+4], s[blk][base2+5]);
        unsigned int a1 = cvtpk(s[blk][base2+2], s[blk][base2+3]);
        unsigned int b1 = cvtpk(s[blk][base2+6], s[blk][base2+7]);
        i32x2 sw0 = __builtin_amdgcn_permlane32_swap((int)a0, (int)b0, false, false);
        i32x2 sw1 = __builtin_amdgcn_permlane32_swap((int)a1, (int)b1, false, false);
        union { bf16x8 v; unsigned int u[4]; } pa;
        pa.u[0] = (unsigned int)sw0[0];   // kv 8hi+{0,1}
        pa.u[1] = (unsigned int)sw1[0];   // kv 8hi+{2,3}
        pa.u[2] = (unsigned int)sw0[1];   // kv 8hi+{4,5}
        pa.u[3] = (unsigned int)sw1[1];   // kv 8hi+{6,7}
        #pragma unroll
        for (int db = 0; db < 4; ++db){
          bf16x8 vf = *reinterpret_cast<const bf16x8*>(
              &Vs[db * 32 + l31][kc * 16 + hi * 8]);
          o[db] = __builtin_amdgcn_mfma_f32_32x32x16_bf16(pa.v, vf, o[db], 0, 0, 0);
        }
      }
      __builtin_amdgcn_s_setprio(0);
    }
    __syncthreads();   // Ks/Vs free for next tile's ds_writes
  }

  if (nc == 1){
    // ---- final (Q<=2): O /= l; write AO in (B,T,C) bf16 ----
    float inv = 1.0f / lrun;                 // this lane's q = qw + l31
    #pragma unroll
    for (int r = 0; r < 16; ++r){
      const int crow = (r & 3) + 8 * (r >> 2) + 4 * hi;
      float ir = __shfl(inv, crow, 32);
      #pragma unroll
      for (int db = 0; db < 4; ++db)
        AO[((size_t)b * T_SEQ + qw + crow) * CDIM + h * HD + db * 32 + l31] =
            f2bf(o[db][r] * ir);
    }
  } else {
    // ---- partial: unnormalized O (bf16) + m,l per row (m in log2 domain) ----
    const int slot = bh * 46 + cumc(Q) + c;
    unsigned short* OpW = Op + (size_t)slot * 128 * 128;
    #pragma unroll
    for (int r = 0; r < 16; ++r){
      const int row = wave * 32 + (r & 3) + 8 * (r >> 2) + 4 * hi;
      #pragma unroll
      for (int db = 0; db < 4; ++db)
        OpW[row * 128 + db * 32 + l31] = f2bf(o[db][r]);
    }
    if (hi == 0){
      Mp[(size_t)slot * 128 + wave * 32 + l31] = mrun;
      Lp[(size_t)slot * 128 + wave * 32 + l31] = lrun;
    }
  }
}

// ---------------- combine partials for q-blocks with nc>=2 (Q=3..15) ----------------
__global__ __launch_bounds__(256) void attn_combine(
    const unsigned short* __restrict__ Op, const float* __restrict__ Mp,
    const float* __restrict__ Lp, unsigned short* __restrict__ AO)
{
  const int Q  = 3 + blockIdx.x;            // 3..15
  const int bh = blockIdx.y;
  const int b = bh / NH, h = bh % NH;
  const int nc = ncq(Q);
  const int slot0 = bh * 46 + cumc(Q);
  #pragma unroll
  for (int u = 0; u < 16; ++u){
    int unit = threadIdx.x + u * 256;       // 128 rows x 32 4-col groups
    int r = unit >> 5, d4 = unit & 31;
    float m = -__builtin_inff();
    for (int cc = 0; cc < nc; ++cc)
      m = fmaxf(m, Mp[(size_t)(slot0 + cc) * 128 + r]);
    float l = 0.f;
    float a0 = 0.f, a1 = 0.f, a2 = 0.f, a3 = 0.f;
    for (int cc = 0; cc < nc; ++cc){
      float w = __builtin_amdgcn_exp2f(Mp[(size_t)(slot0 + cc) * 128 + r] - m);
      l += w * Lp[(size_t)(slot0 + cc) * 128 + r];
      const ushort4 v = *reinterpret_cast<const ushort4*>(
          &Op[((size_t)(slot0 + cc) * 128 + r) * 128 + d4 * 4]);
      a0 += w * bf2f(v.x); a1 += w * bf2f(v.y);
      a2 += w * bf2f(v.z); a3 += w * bf2f(v.w);
    }
    float inv = 1.0f / l;
    ushort4 ov;
    ov.x = f2bf(a0 * inv); ov.y = f2bf(a1 * inv);
    ov.z = f2bf(a2 * inv); ov.w = f2bf(a3 * inv);
    *reinterpret_cast<ushort4*>(
        &AO[((size_t)b * T_SEQ + Q * 128 + r) * CDIM + h * HD + d4 * 4]) = ov;
  }
}

// ---------------- launch ----------------
extern "C" void kernel_launch(void* const* d_in, const int* in_sizes, int n_in,
                              void* d_out, int out_size, void* d_ws, size_t ws_size,
                              hipStream_t stream)
{
  (void)in_sizes; (void)n_in; (void)out_size; (void)ws_size;
  const float* x    = (const float*)d_in[0];
  const float* cosp = (const float*)d_in[1];
  const float* sinp = (const float*)d_in[2];
  const float* Wq   = (const float*)d_in[3];
  const float* Wk   = (const float*)d_in[4];
  const float* Wv   = (const float*)d_in[5];
  const float* Wo   = (const float*)d_in[6];
  float* out = (float*)d_out;

  // workspace layout: bf16 region then partials (~120 MB)
  unsigned short* xb    = (unsigned short*)d_ws;
  unsigned short* Wqkvb = xb    + (size_t)MROWS * CDIM;
  unsigned short* Wob   = Wqkvb + (size_t)NQKV * CDIM;
  unsigned short* QKVb  = Wob   + (size_t)CDIM * CDIM;
  unsigned short* Vtb   = QKVb  + (size_t)MROWS * NQKV;
  unsigned short* AO    = Vtb   + (size_t)MROWS * CDIM;
  unsigned short* Op    = AO    + (size_t)MROWS * CDIM;
  float* Mp = (float*)(Op + (size_t)NSLOT * 128 * 128);
  float* Lp = Mp + (size_t)NSLOT * 128;

  // all f32->bf16 conversions in one launch (x + 4 weight matrices)
  cvt_all<<<8448, 256, 0, stream>>>(x, Wq, Wk, Wv, Wo, xb, Wqkvb);

  // fused QKV projection + RoPE/RMSNorm(+Q-prescale) + V-transpose epilogue
  gemm_bt<1><<<dim3(MROWS / 128, NQKV / 128), 256, 0, stream>>>(
      xb, Wqkvb, QKVb, MROWS, NQKV, CDIM, cosp, sinp, Vtb);
  // causal flash attention, balanced split-KV -> AO (+partials)
  attn_fwd<<<NSLOT, 256, 0, stream>>>(QKVb, Vtb, AO, Op, Mp, Lp);
  attn_combine<<<dim3(13, 24), 256, 0, stream>>>(Op, Mp, Lp, AO);
  // output projection -> f32 d_out
  gemm_bt<0><<<dim3(MROWS / 128, CDIM / 128), 256, 0, stream>>>(
      AO, Wob, out, MROWS, CDIM, CDIM, nullptr, nullptr, nullptr);
}

// Round 21
// 191.184 us; speedup vs baseline: 1.8967x; 1.0876x over previous
//
#include <hip/hip_runtime.h>

#define T_SEQ 2048
#define NH    6
#define HD    128
#define CDIM  768
#define NQKV  2304
#define MROWS 8192   // B*T = 4*2048
#define NSLOT 576    // 24 partial chunks per (b,h) * 24
// 1/sqrt(128) * log2(e): folded into Q during gemm1 epilogue
#define QSCL  0.12754011021989615f

typedef __attribute__((ext_vector_type(8)))  short bf16x8;
typedef __attribute__((ext_vector_type(4)))  float f32x4;
typedef __attribute__((ext_vector_type(16))) float f32x16;
typedef __attribute__((ext_vector_type(2)))  int   i32x2;

__device__ __forceinline__ unsigned short f2bf(float f){
  unsigned int u = __builtin_bit_cast(unsigned int, f);
  u += 0x7fffu + ((u >> 16) & 1u);          // round-to-nearest-even
  return (unsigned short)(u >> 16);
}
__device__ __forceinline__ float bf2f(unsigned short h){
  unsigned int u = ((unsigned int)h) << 16;
  return __builtin_bit_cast(float, u);
}
// raw v_exp_f32: computes 2^x in one instruction (no libm slow path)
__device__ __forceinline__ float ex2(float x){
  return __builtin_amdgcn_exp2f(x);
}
// pack 2 f32 -> 2 bf16 in one instr
__device__ __forceinline__ unsigned int cvtpk(float lo, float hi){
  unsigned int r;
  asm("v_cvt_pk_bf16_f32 %0, %1, %2" : "=v"(r) : "v"(lo), "v"(hi));
  return r;
}

// async global->LDS, 16B per lane; LDS dest is wave-uniform base + lane*16
__device__ __forceinline__ void gload_lds16(const void* g, void* l){
  __builtin_amdgcn_global_load_lds(
      (const __attribute__((address_space(1))) unsigned int*)g,
      (__attribute__((address_space(3))) unsigned int*)l, 16, 0, 0);
}

// chunking: q-block Q (QBLK=128) has 2Q+2 tiles of 64; nc = ceil((2Q+2)/12)
__device__ __forceinline__ int ncq(int Q){
  return Q < 6 ? 1 : Q < 12 ? 2 : 3;
}
// chunks before q-block Q (total 30 per bh)
__device__ __forceinline__ int cumc(int Q){
  return Q < 6 ? Q : Q < 12 ? 6 + 2*(Q-6) : 18 + 3*(Q-12);
}

// ---------------- all f32->bf16 conversions in ONE launch ----------------
// blocks [0,6144): x (MROWS*CDIM); blocks [6144,8448): 4 weights (576 each)
__global__ __launch_bounds__(256) void cvt_all(
    const float* __restrict__ x,
    const float* __restrict__ w0, const float* __restrict__ w1,
    const float* __restrict__ w2, const float* __restrict__ w3,
    unsigned short* __restrict__ xb, unsigned short* __restrict__ wout){
  const int bid = blockIdx.x;
  const float* src;
  unsigned short* dst;
  int i;
  if (bid < 6144){
    src = x; dst = xb;
    i = bid * 256 + threadIdx.x;
  } else {
    const int wb = bid - 6144;
    const int which = wb / 576;
    src = which == 0 ? w0 : which == 1 ? w1 : which == 2 ? w2 : w3;
    dst = wout + (size_t)which * CDIM * CDIM;
    i = (wb % 576) * 256 + threadIdx.x;
  }
  float4 v = reinterpret_cast<const float4*>(src)[i];
  ushort4 o;
  o.x = f2bf(v.x); o.y = f2bf(v.y); o.z = f2bf(v.z); o.w = f2bf(v.w);
  reinterpret_cast<ushort4*>(dst)[i] = o;
}

// ---------------- GEMM: C = A(MxK,bf16) * B(NxK,bf16)^T ----------------
// 128x128 tile, BK=64, global_load_lds(16B) into linear LDS, XOR slot-swizzle
// both-sides. Waves own 32 ROWS x 128 cols (acc[2][8]); EPI=1 fuses
// RoPE+RMSNorm for q/k col-tiles of QKV (Q additionally pre-scaled by
// 1/sqrt(128)*log2e so attention softmax runs in exp2 domain) and
// TRANSPOSES V col-tiles into Vt via LDS bounce.
template<int EPI>
__global__ __launch_bounds__(256) void gemm_bt(
    const unsigned short* __restrict__ A,
    const unsigned short* __restrict__ B,
    void* __restrict__ Cv, int M, int N, int K,
    const float* __restrict__ cosp, const float* __restrict__ sinp,
    unsigned short* __restrict__ Vt)
{
  __shared__ unsigned short sh[128 * 128];  // As = sh[0:8192), Bs = sh[8192:)
  unsigned short* As = sh;
  unsigned short* Bs = sh + 128 * 64;
  const int tid  = threadIdx.x;
  const int lane = tid & 63;
  const int wave = tid >> 6;
  const int lr = lane & 15, lg = lane >> 4;
  const int srow = lane >> 3;               // staging row within 8-row seg
  const int sslot = (lane & 7) ^ (lane >> 3);  // pre-swizzled global slot
  // XCD-aware swizzle; within an XCD, col-tiles vary fastest (A-panel reuse)
  const int gx = gridDim.x, gy = gridDim.y, nwg = gx * gy;
  const int flat = blockIdx.y * gx + blockIdx.x;
  const int nf = (flat & 7) * (nwg >> 3) + (flat >> 3);
  const int row0 = (nf / gy) * 128, col0 = (nf % gy) * 128;
  const int wrow = wave * 32;               // wave's row base within tile

  f32x4 acc[2][8];
  const f32x4 z = {0.f, 0.f, 0.f, 0.f};
  #pragma unroll
  for (int i = 0; i < 2; ++i)
    #pragma unroll
    for (int j = 0; j < 8; ++j) acc[i][j] = z;

  for (int k0 = 0; k0 < K; k0 += 64){
    #pragma unroll
    for (int i = 0; i < 4; ++i){
      int seg = wave * 4 + i;                 // 8 rows per 1KB segment
      int r = seg * 8 + srow;
      gload_lds16(&A[(size_t)(row0 + r) * K + k0 + sslot * 8], &As[seg * 512]);
      gload_lds16(&B[(size_t)(col0 + r) * K + k0 + sslot * 8], &Bs[seg * 512]);
    }
    __syncthreads();
    #pragma unroll
    for (int kk = 0; kk < 64; kk += 32){
      bf16x8 af[2], bfr[8];
      #pragma unroll
      for (int mi = 0; mi < 2; ++mi)
        af[mi] = *reinterpret_cast<const bf16x8*>(
            &As[(wrow + mi*16 + lr) * 64 + ((((kk>>3) + lg) ^ (lr & 7)) * 8)]);
      #pragma unroll
      for (int ni = 0; ni < 8; ++ni)
        bfr[ni] = *reinterpret_cast<const bf16x8*>(
            &Bs[(ni*16 + lr) * 64 + ((((kk>>3) + lg) ^ (lr & 7)) * 8)]);
      #pragma unroll
      for (int mi = 0; mi < 2; ++mi)
        #pragma unroll
        for (int ni = 0; ni < 8; ++ni)
          acc[mi][ni] = __builtin_amdgcn_mfma_f32_16x16x32_bf16(af[mi], bfr[ni], acc[mi][ni], 0, 0, 0);
    }
    __syncthreads();
  }

  if (EPI == 0){
    float* Cf = reinterpret_cast<float*>(Cv);
    #pragma unroll
    for (int mi = 0; mi < 2; ++mi)
      #pragma unroll
      for (int ni = 0; ni < 8; ++ni)
        #pragma unroll
        for (int r = 0; r < 4; ++r)
          Cf[(size_t)(row0 + wrow + mi*16 + lg*4 + r) * N + col0 + ni*16 + lr] = acc[mi][ni][r];
  } else {
    unsigned short* Cb = reinterpret_cast<unsigned short*>(Cv);
    const int ct = col0 >> 7;               // 0..17
    if (ct >= 12){
      // V tile: transpose via LDS bounce -> Vt[(b,h)][d][t]
      const int hh = ct - 12;
      const int b2 = row0 >> 11, t0 = row0 & (T_SEQ - 1);
      #pragma unroll
      for (int mi = 0; mi < 2; ++mi)
        #pragma unroll
        for (int ni = 0; ni < 8; ++ni)
          #pragma unroll
          for (int r = 0; r < 4; ++r){
            const int trow = wrow + mi*16 + lg*4 + r;
            const int col  = ni*16 + lr;
            sh[trow * 128 + (col ^ ((trow & 7) << 4))] = f2bf(acc[mi][ni][r]);
          }
      __syncthreads();
      const int dd = tid >> 1, tq = (tid & 1) * 64;
      unsigned short* dst =
          Vt + ((size_t)(b2 * NH + hh) * HD + dd) * T_SEQ + t0 + tq;
      #pragma unroll
      for (int j8 = 0; j8 < 8; ++j8){
        union { int4 v; unsigned short u[8]; } w;
        #pragma unroll
        for (int jj = 0; jj < 8; ++jj){
          const int tt = tq + j8 * 8 + jj;     // (tt & 7) == jj
          w.u[jj] = sh[tt * 128 + (dd ^ (jj << 4))];
        }
        *reinterpret_cast<int4*>(&dst[j8 * 8]) = w.v;
      }
    } else {
      // Q or K: RoPE (pairs d, d+64 = ni, ni+4) + RMSNorm over 128, then bf16
      // Q tiles (ct<6) additionally scaled by QSCL (softmax exp2-domain)
      const float post = (ct < 6) ? QSCL : 1.0f;
      #pragma unroll
      for (int mi = 0; mi < 2; ++mi){
        #pragma unroll
        for (int r = 0; r < 4; ++r){
          const int row = row0 + wrow + mi*16 + lg*4 + r;
          const int t = row & (T_SEQ - 1);
          float y1[4], y2[4], ssp = 0.f;
          #pragma unroll
          for (int ni = 0; ni < 4; ++ni){
            const int d = ni*16 + lr;
            float c = cosp[t * 64 + d];
            float s = sinp[t * 64 + d];
            float x1 = acc[mi][ni][r], x2 = acc[mi][ni+4][r];
            y1[ni] = x1 * c + x2 * s;
            y2[ni] = x2 * c - x1 * s;
            ssp += y1[ni]*y1[ni] + y2[ni]*y2[ni];
          }
          #pragma unroll
          for (int off = 1; off < 16; off <<= 1) ssp += __shfl_xor(ssp, off);
          const float inv = rsqrtf(ssp * (1.0f / 128.0f) + 1e-15f) * post;
          #pragma unroll
          for (int ni = 0; ni < 4; ++ni){
            const int d = ni*16 + lr;
            Cb[(size_t)row * N + col0 + d]      = f2bf(y1[ni] * inv);
            Cb[(size_t)row * N + col0 + d + 64] = f2bf(y2[ni] * inv);
          }
        }
      }
    }
  }
}

// ---------------- causal flash attention: 32x32 swapped-operand, big-chunk split-KV ----------------
// 4 waves x 32 q-rows (QBLK=128), KVBLK=64, chunks of <=12 tiles -> 720 blocks
// (30 chunks/bh; only Q>=6 splits -> partial traffic halved vs <=7-tile chunks).
// Q pre-scaled by 1/sqrt(128)*log2e -> softmax in exp2 domain via RAW
// v_exp_f32. T14 async-STAGE split staging. XCD-local heads (3 per XCD).
__global__ __launch_bounds__(256) void attn_fwd(
    const unsigned short* __restrict__ QKVb,   // rope'd Q,K in place
    const unsigned short* __restrict__ Vt,     // (B*H, D, T)
    unsigned short* __restrict__ AO,
    unsigned short* __restrict__ Op, float* __restrict__ Mp, float* __restrict__ Lp)
{
  __shared__ unsigned short Ks[64][136];    // K tile [kv][d]
  __shared__ unsigned short Vs[128][72];    // V^T tile [d][kv]
  const int tid = threadIdx.x;
  const int lane = tid & 63, wave = tid >> 6;
  const int l31 = lane & 31, hi = lane >> 5;

  // XCD-aware remap: 720 blocks, 90/XCD = 3 heads' 30 chunks each
  const int flat = blockIdx.x;
  const int nf = (flat & 7) * 90 + (flat >> 3);
  const int bh = nf / 30;
  const int L = 29 - (nf % 30);              // big chunks first within XCD
  int Q, c;
  if (L < 6)       { Q = L; c = 0; }
  else if (L < 18) { int m = L - 6;  Q = 6 + (m >> 1);  c = m & 1; }
  else             { int m = L - 18; Q = 12 + m / 3;    c = m % 3; }
  const int nc = ncq(Q);
  const int tiles = 2 * Q + 2;
  const int base = tiles / nc, rem = tiles % nc;
  const int tbeg = c * base + (c < rem ? c : rem);
  const int tend = tbeg + base + (c < rem ? 1 : 0);
  const int b = bh / NH, h = bh % NH;
  const int qw = Q * 128 + wave * 32;

  const unsigned short* Qp = QKVb + (size_t)(b * T_SEQ) * NQKV + h * HD;
  const unsigned short* Kp = QKVb + (size_t)(b * T_SEQ) * NQKV + CDIM + h * HD;
  const unsigned short* Vp = Vt + (size_t)bh * HD * T_SEQ;

  // staging coords (per thread): K: row kr (64 rows x 16 chunks), V: row vr
  const int kr = tid >> 4, kc4 = (tid & 15) * 8;    // K row, col chunk
  const int vr = tid >> 3, vc4 = (tid & 7) * 8;     // V d-row base

  // Q B-frags: B[k=8hi+j][n=l31] = Q[q=qw+l31][d=16c4+8hi+j]
  bf16x8 qf[8];
  #pragma unroll
  for (int c4 = 0; c4 < 8; ++c4)
    qf[c4] = *reinterpret_cast<const bf16x8*>(
        &Qp[(size_t)(qw + l31) * NQKV + c4 * 16 + hi * 8]);

  f32x16 o[4];
  #pragma unroll
  for (int db = 0; db < 4; ++db)
    #pragma unroll
    for (int r = 0; r < 16; ++r) o[db][r] = 0.f;
  float mrun = -__builtin_inff(), lrun = 0.f;   // mrun in log2 domain

  // prologue: load tile tbeg into registers
  int4 gk0, gk1, gk2, gk3, gv0, gv1, gv2, gv3;
  {
    const int kv0 = tbeg * 64;
    gk0 = *reinterpret_cast<const int4*>(&Kp[(size_t)(kv0 + kr)       * NQKV + kc4]);
    gk1 = *reinterpret_cast<const int4*>(&Kp[(size_t)(kv0 + kr + 16)  * NQKV + kc4]);
    gk2 = *reinterpret_cast<const int4*>(&Kp[(size_t)(kv0 + kr + 32)  * NQKV + kc4]);
    gk3 = *reinterpret_cast<const int4*>(&Kp[(size_t)(kv0 + kr + 48)  * NQKV + kc4]);
    gv0 = *reinterpret_cast<const int4*>(&Vp[(size_t)(vr)       * T_SEQ + kv0 + vc4]);
    gv1 = *reinterpret_cast<const int4*>(&Vp[(size_t)(vr + 32)  * T_SEQ + kv0 + vc4]);
    gv2 = *reinterpret_cast<const int4*>(&Vp[(size_t)(vr + 64)  * T_SEQ + kv0 + vc4]);
    gv3 = *reinterpret_cast<const int4*>(&Vp[(size_t)(vr + 96)  * T_SEQ + kv0 + vc4]);
  }

  for (int t = tbeg; t < tend; ++t){
    // ---- ds_write tile t from registers (vmcnt wait auto-inserted) ----
    *reinterpret_cast<int4*>(&Ks[kr][kc4])        = gk0;
    *reinterpret_cast<int4*>(&Ks[kr + 16][kc4])   = gk1;
    *reinterpret_cast<int4*>(&Ks[kr + 32][kc4])   = gk2;
    *reinterpret_cast<int4*>(&Ks[kr + 48][kc4])   = gk3;
    *reinterpret_cast<int4*>(&Vs[vr][vc4])        = gv0;
    *reinterpret_cast<int4*>(&Vs[vr + 32][vc4])   = gv1;
    *reinterpret_cast<int4*>(&Vs[vr + 64][vc4])   = gv2;
    *reinterpret_cast<int4*>(&Vs[vr + 96][vc4])   = gv3;
    __syncthreads();

    // ---- issue tile t+1 loads (latency hides under compute below) ----
    if (t + 1 < tend){
      const int kn = (t + 1) * 64;
      gk0 = *reinterpret_cast<const int4*>(&Kp[(size_t)(kn + kr)       * NQKV + kc4]);
      gk1 = *reinterpret_cast<const int4*>(&Kp[(size_t)(kn + kr + 16)  * NQKV + kc4]);
      gk2 = *reinterpret_cast<const int4*>(&Kp[(size_t)(kn + kr + 32)  * NQKV + kc4]);
      gk3 = *reinterpret_cast<const int4*>(&Kp[(size_t)(kn + kr + 48)  * NQKV + kc4]);
      gv0 = *reinterpret_cast<const int4*>(&Vp[(size_t)(vr)       * T_SEQ + kn + vc4]);
      gv1 = *reinterpret_cast<const int4*>(&Vp[(size_t)(vr + 32)  * T_SEQ + kn + vc4]);
      gv2 = *reinterpret_cast<const int4*>(&Vp[(size_t)(vr + 64)  * T_SEQ + kn + vc4]);
      gv3 = *reinterpret_cast<const int4*>(&Vp[(size_t)(vr + 96)  * T_SEQ + kn + vc4]);
    }

    const int kv0 = t * 64;
    if (kv0 <= qw + 31){                     // tile has unmasked work for this wave
      // ---- S^T = K Q^T (Q pre-scaled): lane holds S[kv][q=qw+l31] ----
      f32x16 s[2];
      #pragma unroll
      for (int r = 0; r < 16; ++r){ s[0][r] = 0.f; s[1][r] = 0.f; }
      __builtin_amdgcn_s_setprio(1);
      #pragma unroll
      for (int c4 = 0; c4 < 8; ++c4){
        bf16x8 k0 = *reinterpret_cast<const bf16x8*>(&Ks[l31][c4 * 16 + hi * 8]);
        bf16x8 k1 = *reinterpret_cast<const bf16x8*>(&Ks[32 + l31][c4 * 16 + hi * 8]);
        s[0] = __builtin_amdgcn_mfma_f32_32x32x16_bf16(k0, qf[c4], s[0], 0, 0, 0);
        s[1] = __builtin_amdgcn_mfma_f32_32x32x16_bf16(k1, qf[c4], s[1], 0, 0, 0);
      }
      __builtin_amdgcn_s_setprio(0);

      // ---- causal mask (diagonal tiles only; interior: no scale work) ----
      const int qg = qw + l31;
      if (kv0 + 63 > qw){
        #pragma unroll
        for (int blk = 0; blk < 2; ++blk)
          #pragma unroll
          for (int r = 0; r < 16; ++r){
            int kg = kv0 + 32 * blk + (r & 3) + 8 * (r >> 2) + 4 * hi;
            s[blk][r] = (kg <= qg) ? s[blk][r] : -__builtin_inff();
          }
      }

      // ---- row max: tree over own 32 + 1 cross-half shuffle ----
      float t8[8];
      #pragma unroll
      for (int blk = 0; blk < 2; ++blk)
        #pragma unroll
        for (int j = 0; j < 4; ++j)
          t8[blk * 4 + j] = fmaxf(fmaxf(s[blk][4*j], s[blk][4*j+1]),
                                  fmaxf(s[blk][4*j+2], s[blk][4*j+3]));
      float pm = fmaxf(fmaxf(fmaxf(t8[0], t8[1]), fmaxf(t8[2], t8[3])),
                       fmaxf(fmaxf(t8[4], t8[5]), fmaxf(t8[6], t8[7])));
      pm = fmaxf(pm, __shfl_xor(pm, 32));

      // ---- deferred rescale (wave-uniform; exp2 domain, raw v_exp) ----
      if (__any(pm > mrun)){
        float mn = fmaxf(mrun, pm);
        float scf = (mrun == -__builtin_inff()) ? 0.f : ex2(mrun - mn);
        mrun = mn; lrun *= scf;
        #pragma unroll
        for (int r = 0; r < 16; ++r){
          float scr = __shfl(scf, (r & 3) + 8 * (r >> 2) + 4 * hi, 32);
          #pragma unroll
          for (int db = 0; db < 4; ++db) o[db][r] *= scr;
        }
      }

      // ---- exp2 (raw v_exp_f32) + row sum ----
      float a8[8];
      #pragma unroll
      for (int blk = 0; blk < 2; ++blk)
        #pragma unroll
        for (int j = 0; j < 4; ++j){
          float p0 = ex2(s[blk][4*j]   - mrun);
          float p1 = ex2(s[blk][4*j+1] - mrun);
          float p2 = ex2(s[blk][4*j+2] - mrun);
          float p3 = ex2(s[blk][4*j+3] - mrun);
          s[blk][4*j] = p0; s[blk][4*j+1] = p1; s[blk][4*j+2] = p2; s[blk][4*j+3] = p3;
          a8[blk * 4 + j] = (p0 + p1) + (p2 + p3);
        }
      float ls = ((a8[0] + a8[1]) + (a8[2] + a8[3])) + ((a8[4] + a8[5]) + (a8[6] + a8[7]));
      lrun += ls + __shfl_xor(ls, 32);

      // ---- O += P V : A-frags via cvt_pk + permlane32_swap ----
      __builtin_amdgcn_s_setprio(1);
      #pragma unroll
      for (int kc = 0; kc < 4; ++kc){
        const int blk = kc >> 1, base2 = (kc & 1) * 8;
        unsigned int a0 = cvtpk(s[blk][base2+0], s[blk][base2+1]);
        unsigned int b0 = cvtpk(s[blk][base2+4], s[blk][base2+5]);
        unsigned int a1 = cvtpk(s[blk][base2+2], s[blk][base2+3]);
        unsigned int b1 = cvtpk(s[blk][base2+6], s[blk][base2+7]);
        i32x2 sw0 = __builtin_amdgcn_permlane32_swap((int)a0, (int)b0, false, false);
        i32x2 sw1 = __builtin_amdgcn_permlane32_swap((int)a1, (int)b1, false, false);
        union { bf16x8 v; unsigned int u[4]; } pa;
        pa.u[0] = (unsigned int)sw0[0];   // kv 8hi+{0,1}
        pa.u[1] = (unsigned int)sw1[0];   // kv 8hi+{2,3}
        pa.u[2] = (unsigned int)sw0[1];   // kv 8hi+{4,5}
        pa.u[3] = (unsigned int)sw1[1];   // kv 8hi+{6,7}
        #pragma unroll
        for (int db = 0; db < 4; ++db){
          bf16x8 vf = *reinterpret_cast<const bf16x8*>(
              &Vs[db * 32 + l31][kc * 16 + hi * 8]);
          o[db] = __builtin_amdgcn_mfma_f32_32x32x16_bf16(pa.v, vf, o[db], 0, 0, 0);
        }
      }
      __builtin_amdgcn_s_setprio(0);
    }
    __syncthreads();   // Ks/Vs free for next tile's ds_writes
  }

  if (nc == 1){
    // ---- final (Q<6): O /= l; write AO in (B,T,C) bf16 ----
    float inv = 1.0f / lrun;                 // this lane's q = qw + l31
    #pragma unroll
    for (int r = 0; r < 16; ++r){
      const int crow = (r & 3) + 8 * (r >> 2) + 4 * hi;
      float ir = __shfl(inv, crow, 32);
      #pragma unroll
      for (int db = 0; db < 4; ++db)
        AO[((size_t)b * T_SEQ + qw + crow) * CDIM + h * HD + db * 32 + l31] =
            f2bf(o[db][r] * ir);
    }
  } else {
    // ---- partial: unnormalized O (bf16) + m,l per row (m in log2 domain) ----
    const int slot = bh * 24 + (cumc(Q) - 6) + c;   // partial slots start at Q=6
    unsigned short* OpW = Op + (size_t)slot * 128 * 128;
    #pragma unroll
    for (int r = 0; r < 16; ++r){
      const int row = wave * 32 + (r & 3) + 8 * (r >> 2) + 4 * hi;
      #pragma unroll
      for (int db = 0; db < 4; ++db)
        OpW[row * 128 + db * 32 + l31] = f2bf(o[db][r]);
    }
    if (hi == 0){
      Mp[(size_t)slot * 128 + wave * 32 + l31] = mrun;
      Lp[(size_t)slot * 128 + wave * 32 + l31] = lrun;
    }
  }
}

// ---------------- combine partials for q-blocks with nc>=2 (Q=6..15) ----------------
__global__ __launch_bounds__(256) void attn_combine(
    const unsigned short* __restrict__ Op, const float* __restrict__ Mp,
    const float* __restrict__ Lp, unsigned short* __restrict__ AO)
{
  const int Q  = 6 + blockIdx.x;            // 6..15
  const int bh = blockIdx.y;
  const int b = bh / NH, h = bh % NH;
  const int nc = ncq(Q);
  const int slot0 = bh * 24 + (cumc(Q) - 6);
  #pragma unroll
  for (int u = 0; u < 16; ++u){
    int unit = threadIdx.x + u * 256;       // 128 rows x 32 4-col groups
    int r = unit >> 5, d4 = unit & 31;
    float m = -__builtin_inff();
    for (int cc = 0; cc < nc; ++cc)
      m = fmaxf(m, Mp[(size_t)(slot0 + cc) * 128 + r]);
    float l = 0.f;
    float a0 = 0.f, a1 = 0.f, a2 = 0.f, a3 = 0.f;
    for (int cc = 0; cc < nc; ++cc){
      float w = __builtin_amdgcn_exp2f(Mp[(size_t)(slot0 + cc) * 128 + r] - m);
      l += w * Lp[(size_t)(slot0 + cc) * 128 + r];
      const ushort4 v = *reinterpret_cast<const ushort4*>(
          &Op[((size_t)(slot0 + cc) * 128 + r) * 128 + d4 * 4]);
      a0 += w * bf2f(v.x); a1 += w * bf2f(v.y);
      a2 += w * bf2f(v.z); a3 += w * bf2f(v.w);
    }
    float inv = 1.0f / l;
    ushort4 ov;
    ov.x = f2bf(a0 * inv); ov.y = f2bf(a1 * inv);
    ov.z = f2bf(a2 * inv); ov.w = f2bf(a3 * inv);
    *reinterpret_cast<ushort4*>(
        &AO[((size_t)b * T_SEQ + Q * 128 + r) * CDIM + h * HD + d4 * 4]) = ov;
  }
}

// ---------------- launch ----------------
extern "C" void kernel_launch(void* const* d_in, const int* in_sizes, int n_in,
                              void* d_out, int out_size, void* d_ws, size_t ws_size,
                              hipStream_t stream)
{
  (void)in_sizes; (void)n_in; (void)out_size; (void)ws_size;
  const float* x    = (const float*)d_in[0];
  const float* cosp = (const float*)d_in[1];
  const float* sinp = (const float*)d_in[2];
  const float* Wq   = (const float*)d_in[3];
  const float* Wk   = (const float*)d_in[4];
  const float* Wv   = (const float*)d_in[5];
  const float* Wo   = (const float*)d_in[6];
  float* out = (float*)d_out;

  // workspace layout: bf16 region then partials (~101 MB)
  unsigned short* xb    = (unsigned short*)d_ws;
  unsigned short* Wqkvb = xb    + (size_t)MROWS * CDIM;
  unsigned short* Wob   = Wqkvb + (size_t)NQKV * CDIM;
  unsigned short* QKVb  = Wob   + (size_t)CDIM * CDIM;
  unsigned short* Vtb   = QKVb  + (size_t)MROWS * NQKV;
  unsigned short* AO    = Vtb   + (size_t)MROWS * CDIM;
  unsigned short* Op    = AO    + (size_t)MROWS * CDIM;
  float* Mp = (float*)(Op + (size_t)NSLOT * 128 * 128);
  float* Lp = Mp + (size_t)NSLOT * 128;

  // all f32->bf16 conversions in one launch (x + 4 weight matrices)
  cvt_all<<<8448, 256, 0, stream>>>(x, Wq, Wk, Wv, Wo, xb, Wqkvb);

  // fused QKV projection + RoPE/RMSNorm(+Q-prescale) + V-transpose epilogue
  gemm_bt<1><<<dim3(MROWS / 128, NQKV / 128), 256, 0, stream>>>(
      xb, Wqkvb, QKVb, MROWS, NQKV, CDIM, cosp, sinp, Vtb);
  // causal flash attention, big-chunk split-KV -> AO (+partials)
  attn_fwd<<<720, 256, 0, stream>>>(QKVb, Vtb, AO, Op, Mp, Lp);
  attn_combine<<<dim3(10, 24), 256, 0, stream>>>(Op, Mp, Lp, AO);
  // output projection -> f32 d_out
  gemm_bt<0><<<dim3(MROWS / 128, CDIM / 128), 256, 0, stream>>>(
      AO, Wob, out, MROWS, CDIM, CDIM, nullptr, nullptr, nullptr);
}

// Round 22
// 176.640 us; speedup vs baseline: 2.0529x; 1.0823x over previous
//
#include <hip/hip_runtime.h>

#define T_SEQ 2048
#define NH    6
#define HD    128
#define CDIM  768
#define NQKV  2304
#define MROWS 8192   // B*T = 4*2048
#define NSLOT 384    // 16 partial chunks per (b,h) * 24
// 1/sqrt(128) * log2(e): folded into Q during gemm1 epilogue
#define QSCL  0.12754011021989615f

typedef __attribute__((ext_vector_type(8)))  short bf16x8;
typedef __attribute__((ext_vector_type(4)))  float f32x4;
typedef __attribute__((ext_vector_type(16))) float f32x16;
typedef __attribute__((ext_vector_type(2)))  int   i32x2;

__device__ __forceinline__ unsigned short f2bf(float f){
  unsigned int u = __builtin_bit_cast(unsigned int, f);
  u += 0x7fffu + ((u >> 16) & 1u);          // round-to-nearest-even
  return (unsigned short)(u >> 16);
}
__device__ __forceinline__ float bf2f(unsigned short h){
  unsigned int u = ((unsigned int)h) << 16;
  return __builtin_bit_cast(float, u);
}
// raw v_exp_f32: computes 2^x in one instruction (no libm slow path)
__device__ __forceinline__ float ex2(float x){
  return __builtin_amdgcn_exp2f(x);
}
// pack 2 f32 -> 2 bf16 in one instr
__device__ __forceinline__ unsigned int cvtpk(float lo, float hi){
  unsigned int r;
  asm("v_cvt_pk_bf16_f32 %0, %1, %2" : "=v"(r) : "v"(lo), "v"(hi));
  return r;
}

// async global->LDS, 16B per lane; LDS dest is wave-uniform base + lane*16
__device__ __forceinline__ void gload_lds16(const void* g, void* l){
  __builtin_amdgcn_global_load_lds(
      (const __attribute__((address_space(1))) unsigned int*)g,
      (__attribute__((address_space(3))) unsigned int*)l, 16, 0, 0);
}

// chunking: q-block Q (QBLK=128) has 2Q+2 tiles of 64; nc = ceil((2Q+2)/16)
__device__ __forceinline__ int ncq(int Q){
  return Q < 8 ? 1 : 2;
}
// chunks before q-block Q (total 24 per bh)
__device__ __forceinline__ int cumc(int Q){
  return Q < 8 ? Q : 8 + 2*(Q-8);
}

// ---------------- all f32->bf16 conversions in ONE launch ----------------
// blocks [0,6144): x (MROWS*CDIM); blocks [6144,8448): 4 weights (576 each)
__global__ __launch_bounds__(256) void cvt_all(
    const float* __restrict__ x,
    const float* __restrict__ w0, const float* __restrict__ w1,
    const float* __restrict__ w2, const float* __restrict__ w3,
    unsigned short* __restrict__ xb, unsigned short* __restrict__ wout){
  const int bid = blockIdx.x;
  const float* src;
  unsigned short* dst;
  int i;
  if (bid < 6144){
    src = x; dst = xb;
    i = bid * 256 + threadIdx.x;
  } else {
    const int wb = bid - 6144;
    const int which = wb / 576;
    src = which == 0 ? w0 : which == 1 ? w1 : which == 2 ? w2 : w3;
    dst = wout + (size_t)which * CDIM * CDIM;
    i = (wb % 576) * 256 + threadIdx.x;
  }
  float4 v = reinterpret_cast<const float4*>(src)[i];
  ushort4 o;
  o.x = f2bf(v.x); o.y = f2bf(v.y); o.z = f2bf(v.z); o.w = f2bf(v.w);
  reinterpret_cast<ushort4*>(dst)[i] = o;
}

// ---------------- GEMM: C = A(MxK,bf16) * B(NxK,bf16)^T ----------------
// 128x128 tile, BK=64, global_load_lds(16B) into linear LDS, XOR slot-swizzle
// both-sides. Waves own 32 ROWS x 128 cols (acc[2][8]); EPI=1 fuses
// RoPE+RMSNorm for q/k col-tiles of QKV (Q additionally pre-scaled by
// 1/sqrt(128)*log2e so attention softmax runs in exp2 domain) and
// TRANSPOSES V col-tiles into Vt via LDS bounce.
template<int EPI>
__global__ __launch_bounds__(256) void gemm_bt(
    const unsigned short* __restrict__ A,
    const unsigned short* __restrict__ B,
    void* __restrict__ Cv, int M, int N, int K,
    const float* __restrict__ cosp, const float* __restrict__ sinp,
    unsigned short* __restrict__ Vt)
{
  __shared__ unsigned short sh[128 * 128];  // As = sh[0:8192), Bs = sh[8192:)
  unsigned short* As = sh;
  unsigned short* Bs = sh + 128 * 64;
  const int tid  = threadIdx.x;
  const int lane = tid & 63;
  const int wave = tid >> 6;
  const int lr = lane & 15, lg = lane >> 4;
  const int srow = lane >> 3;               // staging row within 8-row seg
  const int sslot = (lane & 7) ^ (lane >> 3);  // pre-swizzled global slot
  // XCD-aware swizzle; within an XCD, col-tiles vary fastest (A-panel reuse)
  const int gx = gridDim.x, gy = gridDim.y, nwg = gx * gy;
  const int flat = blockIdx.y * gx + blockIdx.x;
  const int nf = (flat & 7) * (nwg >> 3) + (flat >> 3);
  const int row0 = (nf / gy) * 128, col0 = (nf % gy) * 128;
  const int wrow = wave * 32;               // wave's row base within tile

  f32x4 acc[2][8];
  const f32x4 z = {0.f, 0.f, 0.f, 0.f};
  #pragma unroll
  for (int i = 0; i < 2; ++i)
    #pragma unroll
    for (int j = 0; j < 8; ++j) acc[i][j] = z;

  for (int k0 = 0; k0 < K; k0 += 64){
    #pragma unroll
    for (int i = 0; i < 4; ++i){
      int seg = wave * 4 + i;                 // 8 rows per 1KB segment
      int r = seg * 8 + srow;
      gload_lds16(&A[(size_t)(row0 + r) * K + k0 + sslot * 8], &As[seg * 512]);
      gload_lds16(&B[(size_t)(col0 + r) * K + k0 + sslot * 8], &Bs[seg * 512]);
    }
    __syncthreads();
    #pragma unroll
    for (int kk = 0; kk < 64; kk += 32){
      bf16x8 af[2], bfr[8];
      #pragma unroll
      for (int mi = 0; mi < 2; ++mi)
        af[mi] = *reinterpret_cast<const bf16x8*>(
            &As[(wrow + mi*16 + lr) * 64 + ((((kk>>3) + lg) ^ (lr & 7)) * 8)]);
      #pragma unroll
      for (int ni = 0; ni < 8; ++ni)
        bfr[ni] = *reinterpret_cast<const bf16x8*>(
            &Bs[(ni*16 + lr) * 64 + ((((kk>>3) + lg) ^ (lr & 7)) * 8)]);
      #pragma unroll
      for (int mi = 0; mi < 2; ++mi)
        #pragma unroll
        for (int ni = 0; ni < 8; ++ni)
          acc[mi][ni] = __builtin_amdgcn_mfma_f32_16x16x32_bf16(af[mi], bfr[ni], acc[mi][ni], 0, 0, 0);
    }
    __syncthreads();
  }

  if (EPI == 0){
    float* Cf = reinterpret_cast<float*>(Cv);
    #pragma unroll
    for (int mi = 0; mi < 2; ++mi)
      #pragma unroll
      for (int ni = 0; ni < 8; ++ni)
        #pragma unroll
        for (int r = 0; r < 4; ++r)
          Cf[(size_t)(row0 + wrow + mi*16 + lg*4 + r) * N + col0 + ni*16 + lr] = acc[mi][ni][r];
  } else {
    unsigned short* Cb = reinterpret_cast<unsigned short*>(Cv);
    const int ct = col0 >> 7;               // 0..17
    if (ct >= 12){
      // V tile: transpose via LDS bounce -> Vt[(b,h)][d][t]
      const int hh = ct - 12;
      const int b2 = row0 >> 11, t0 = row0 & (T_SEQ - 1);
      #pragma unroll
      for (int mi = 0; mi < 2; ++mi)
        #pragma unroll
        for (int ni = 0; ni < 8; ++ni)
          #pragma unroll
          for (int r = 0; r < 4; ++r){
            const int trow = wrow + mi*16 + lg*4 + r;
            const int col  = ni*16 + lr;
            sh[trow * 128 + (col ^ ((trow & 7) << 4))] = f2bf(acc[mi][ni][r]);
          }
      __syncthreads();
      const int dd = tid >> 1, tq = (tid & 1) * 64;
      unsigned short* dst =
          Vt + ((size_t)(b2 * NH + hh) * HD + dd) * T_SEQ + t0 + tq;
      #pragma unroll
      for (int j8 = 0; j8 < 8; ++j8){
        union { int4 v; unsigned short u[8]; } w;
        #pragma unroll
        for (int jj = 0; jj < 8; ++jj){
          const int tt = tq + j8 * 8 + jj;     // (tt & 7) == jj
          w.u[jj] = sh[tt * 128 + (dd ^ (jj << 4))];
        }
        *reinterpret_cast<int4*>(&dst[j8 * 8]) = w.v;
      }
    } else {
      // Q or K: RoPE (pairs d, d+64 = ni, ni+4) + RMSNorm over 128, then bf16
      // Q tiles (ct<6) additionally scaled by QSCL (softmax exp2-domain)
      const float post = (ct < 6) ? QSCL : 1.0f;
      #pragma unroll
      for (int mi = 0; mi < 2; ++mi){
        #pragma unroll
        for (int r = 0; r < 4; ++r){
          const int row = row0 + wrow + mi*16 + lg*4 + r;
          const int t = row & (T_SEQ - 1);
          float y1[4], y2[4], ssp = 0.f;
          #pragma unroll
          for (int ni = 0; ni < 4; ++ni){
            const int d = ni*16 + lr;
            float c = cosp[t * 64 + d];
            float s = sinp[t * 64 + d];
            float x1 = acc[mi][ni][r], x2 = acc[mi][ni+4][r];
            y1[ni] = x1 * c + x2 * s;
            y2[ni] = x2 * c - x1 * s;
            ssp += y1[ni]*y1[ni] + y2[ni]*y2[ni];
          }
          #pragma unroll
          for (int off = 1; off < 16; off <<= 1) ssp += __shfl_xor(ssp, off);
          const float inv = rsqrtf(ssp * (1.0f / 128.0f) + 1e-15f) * post;
          #pragma unroll
          for (int ni = 0; ni < 4; ++ni){
            const int d = ni*16 + lr;
            Cb[(size_t)row * N + col0 + d]      = f2bf(y1[ni] * inv);
            Cb[(size_t)row * N + col0 + d + 64] = f2bf(y2[ni] * inv);
          }
        }
      }
    }
  }
}

// ---------------- causal flash attention: 32x32 swapped-operand, big-chunk split-KV ----------------
// 4 waves x 32 q-rows (QBLK=128), KVBLK=64, chunks of <=16 tiles -> 576 blocks
// (24 chunks/bh; only Q>=8 splits, always into 2 even halves -> partial
// traffic halved again vs <=12-tile chunks).
// Q pre-scaled by 1/sqrt(128)*log2e -> softmax in exp2 domain via RAW
// v_exp_f32. T14 async-STAGE split staging. XCD-local heads (3 per XCD).
__global__ __launch_bounds__(256) void attn_fwd(
    const unsigned short* __restrict__ QKVb,   // rope'd Q,K in place
    const unsigned short* __restrict__ Vt,     // (B*H, D, T)
    unsigned short* __restrict__ AO,
    unsigned short* __restrict__ Op, float* __restrict__ Mp, float* __restrict__ Lp)
{
  __shared__ unsigned short Ks[64][136];    // K tile [kv][d]
  __shared__ unsigned short Vs[128][72];    // V^T tile [d][kv]
  const int tid = threadIdx.x;
  const int lane = tid & 63, wave = tid >> 6;
  const int l31 = lane & 31, hi = lane >> 5;

  // XCD-aware remap: 576 blocks, 72/XCD = 3 heads' 24 chunks each
  const int flat = blockIdx.x;
  const int nf = (flat & 7) * 72 + (flat >> 3);
  const int bh = nf / 24;
  const int L = 23 - (nf % 24);              // big chunks first within XCD
  int Q, c;
  if (L < 8){ Q = L; c = 0; }
  else      { int m = L - 8; Q = 8 + (m >> 1); c = m & 1; }
  const int nc = ncq(Q);
  const int tiles = 2 * Q + 2;
  const int half = tiles >> 1;               // tiles always even
  const int tbeg = (nc == 1) ? 0    : c * half;
  const int tend = (nc == 1) ? tiles : tbeg + half;
  const int b = bh / NH, h = bh % NH;
  const int qw = Q * 128 + wave * 32;

  const unsigned short* Qp = QKVb + (size_t)(b * T_SEQ) * NQKV + h * HD;
  const unsigned short* Kp = QKVb + (size_t)(b * T_SEQ) * NQKV + CDIM + h * HD;
  const unsigned short* Vp = Vt + (size_t)bh * HD * T_SEQ;

  // staging coords (per thread): K: row kr (64 rows x 16 chunks), V: row vr
  const int kr = tid >> 4, kc4 = (tid & 15) * 8;    // K row, col chunk
  const int vr = tid >> 3, vc4 = (tid & 7) * 8;     // V d-row base

  // Q B-frags: B[k=8hi+j][n=l31] = Q[q=qw+l31][d=16c4+8hi+j]
  bf16x8 qf[8];
  #pragma unroll
  for (int c4 = 0; c4 < 8; ++c4)
    qf[c4] = *reinterpret_cast<const bf16x8*>(
        &Qp[(size_t)(qw + l31) * NQKV + c4 * 16 + hi * 8]);

  f32x16 o[4];
  #pragma unroll
  for (int db = 0; db < 4; ++db)
    #pragma unroll
    for (int r = 0; r < 16; ++r) o[db][r] = 0.f;
  float mrun = -__builtin_inff(), lrun = 0.f;   // mrun in log2 domain

  // prologue: load tile tbeg into registers
  int4 gk0, gk1, gk2, gk3, gv0, gv1, gv2, gv3;
  {
    const int kv0 = tbeg * 64;
    gk0 = *reinterpret_cast<const int4*>(&Kp[(size_t)(kv0 + kr)       * NQKV + kc4]);
    gk1 = *reinterpret_cast<const int4*>(&Kp[(size_t)(kv0 + kr + 16)  * NQKV + kc4]);
    gk2 = *reinterpret_cast<const int4*>(&Kp[(size_t)(kv0 + kr + 32)  * NQKV + kc4]);
    gk3 = *reinterpret_cast<const int4*>(&Kp[(size_t)(kv0 + kr + 48)  * NQKV + kc4]);
    gv0 = *reinterpret_cast<const int4*>(&Vp[(size_t)(vr)       * T_SEQ + kv0 + vc4]);
    gv1 = *reinterpret_cast<const int4*>(&Vp[(size_t)(vr + 32)  * T_SEQ + kv0 + vc4]);
    gv2 = *reinterpret_cast<const int4*>(&Vp[(size_t)(vr + 64)  * T_SEQ + kv0 + vc4]);
    gv3 = *reinterpret_cast<const int4*>(&Vp[(size_t)(vr + 96)  * T_SEQ + kv0 + vc4]);
  }

  for (int t = tbeg; t < tend; ++t){
    // ---- ds_write tile t from registers (vmcnt wait auto-inserted) ----
    *reinterpret_cast<int4*>(&Ks[kr][kc4])        = gk0;
    *reinterpret_cast<int4*>(&Ks[kr + 16][kc4])   = gk1;
    *reinterpret_cast<int4*>(&Ks[kr + 32][kc4])   = gk2;
    *reinterpret_cast<int4*>(&Ks[kr + 48][kc4])   = gk3;
    *reinterpret_cast<int4*>(&Vs[vr][vc4])        = gv0;
    *reinterpret_cast<int4*>(&Vs[vr + 32][vc4])   = gv1;
    *reinterpret_cast<int4*>(&Vs[vr + 64][vc4])   = gv2;
    *reinterpret_cast<int4*>(&Vs[vr + 96][vc4])   = gv3;
    __syncthreads();

    // ---- issue tile t+1 loads (latency hides under compute below) ----
    if (t + 1 < tend){
      const int kn = (t + 1) * 64;
      gk0 = *reinterpret_cast<const int4*>(&Kp[(size_t)(kn + kr)       * NQKV + kc4]);
      gk1 = *reinterpret_cast<const int4*>(&Kp[(size_t)(kn + kr + 16)  * NQKV + kc4]);
      gk2 = *reinterpret_cast<const int4*>(&Kp[(size_t)(kn + kr + 32)  * NQKV + kc4]);
      gk3 = *reinterpret_cast<const int4*>(&Kp[(size_t)(kn + kr + 48)  * NQKV + kc4]);
      gv0 = *reinterpret_cast<const int4*>(&Vp[(size_t)(vr)       * T_SEQ + kn + vc4]);
      gv1 = *reinterpret_cast<const int4*>(&Vp[(size_t)(vr + 32)  * T_SEQ + kn + vc4]);
      gv2 = *reinterpret_cast<const int4*>(&Vp[(size_t)(vr + 64)  * T_SEQ + kn + vc4]);
      gv3 = *reinterpret_cast<const int4*>(&Vp[(size_t)(vr + 96)  * T_SEQ + kn + vc4]);
    }

    const int kv0 = t * 64;
    if (kv0 <= qw + 31){                     // tile has unmasked work for this wave
      // ---- S^T = K Q^T (Q pre-scaled): lane holds S[kv][q=qw+l31] ----
      f32x16 s[2];
      #pragma unroll
      for (int r = 0; r < 16; ++r){ s[0][r] = 0.f; s[1][r] = 0.f; }
      __builtin_amdgcn_s_setprio(1);
      #pragma unroll
      for (int c4 = 0; c4 < 8; ++c4){
        bf16x8 k0 = *reinterpret_cast<const bf16x8*>(&Ks[l31][c4 * 16 + hi * 8]);
        bf16x8 k1 = *reinterpret_cast<const bf16x8*>(&Ks[32 + l31][c4 * 16 + hi * 8]);
        s[0] = __builtin_amdgcn_mfma_f32_32x32x16_bf16(k0, qf[c4], s[0], 0, 0, 0);
        s[1] = __builtin_amdgcn_mfma_f32_32x32x16_bf16(k1, qf[c4], s[1], 0, 0, 0);
      }
      __builtin_amdgcn_s_setprio(0);

      // ---- causal mask (diagonal tiles only; interior: no scale work) ----
      const int qg = qw + l31;
      if (kv0 + 63 > qw){
        #pragma unroll
        for (int blk = 0; blk < 2; ++blk)
          #pragma unroll
          for (int r = 0; r < 16; ++r){
            int kg = kv0 + 32 * blk + (r & 3) + 8 * (r >> 2) + 4 * hi;
            s[blk][r] = (kg <= qg) ? s[blk][r] : -__builtin_inff();
          }
      }

      // ---- row max: tree over own 32 + 1 cross-half shuffle ----
      float t8[8];
      #pragma unroll
      for (int blk = 0; blk < 2; ++blk)
        #pragma unroll
        for (int j = 0; j < 4; ++j)
          t8[blk * 4 + j] = fmaxf(fmaxf(s[blk][4*j], s[blk][4*j+1]),
                                  fmaxf(s[blk][4*j+2], s[blk][4*j+3]));
      float pm = fmaxf(fmaxf(fmaxf(t8[0], t8[1]), fmaxf(t8[2], t8[3])),
                       fmaxf(fmaxf(t8[4], t8[5]), fmaxf(t8[6], t8[7])));
      pm = fmaxf(pm, __shfl_xor(pm, 32));

      // ---- deferred rescale (wave-uniform; exp2 domain, raw v_exp) ----
      if (__any(pm > mrun)){
        float mn = fmaxf(mrun, pm);
        float scf = (mrun == -__builtin_inff()) ? 0.f : ex2(mrun - mn);
        mrun = mn; lrun *= scf;
        #pragma unroll
        for (int r = 0; r < 16; ++r){
          float scr = __shfl(scf, (r & 3) + 8 * (r >> 2) + 4 * hi, 32);
          #pragma unroll
          for (int db = 0; db < 4; ++db) o[db][r] *= scr;
        }
      }

      // ---- exp2 (raw v_exp_f32) + row sum ----
      float a8[8];
      #pragma unroll
      for (int blk = 0; blk < 2; ++blk)
        #pragma unroll
        for (int j = 0; j < 4; ++j){
          float p0 = ex2(s[blk][4*j]   - mrun);
          float p1 = ex2(s[blk][4*j+1] - mrun);
          float p2 = ex2(s[blk][4*j+2] - mrun);
          float p3 = ex2(s[blk][4*j+3] - mrun);
          s[blk][4*j] = p0; s[blk][4*j+1] = p1; s[blk][4*j+2] = p2; s[blk][4*j+3] = p3;
          a8[blk * 4 + j] = (p0 + p1) + (p2 + p3);
        }
      float ls = ((a8[0] + a8[1]) + (a8[2] + a8[3])) + ((a8[4] + a8[5]) + (a8[6] + a8[7]));
      lrun += ls + __shfl_xor(ls, 32);

      // ---- O += P V : A-frags via cvt_pk + permlane32_swap ----
      __builtin_amdgcn_s_setprio(1);
      #pragma unroll
      for (int kc = 0; kc < 4; ++kc){
        const int blk = kc >> 1, base2 = (kc & 1) * 8;
        unsigned int a0 = cvtpk(s[blk][base2+0], s[blk][base2+1]);
        unsigned int b0 = cvtpk(s[blk][base2+4], s[blk][base2+5]);
        unsigned int a1 = cvtpk(s[blk][base2+2], s[blk][base2+3]);
        unsigned int b1 = cvtpk(s[blk][base2+6], s[blk][base2+7]);
        i32x2 sw0 = __builtin_amdgcn_permlane32_swap((int)a0, (int)b0, false, false);
        i32x2 sw1 = __builtin_amdgcn_permlane32_swap((int)a1, (int)b1, false, false);
        union { bf16x8 v; unsigned int u[4]; } pa;
        pa.u[0] = (unsigned int)sw0[0];   // kv 8hi+{0,1}
        pa.u[1] = (unsigned int)sw1[0];   // kv 8hi+{2,3}
        pa.u[2] = (unsigned int)sw0[1];   // kv 8hi+{4,5}
        pa.u[3] = (unsigned int)sw1[1];   // kv 8hi+{6,7}
        #pragma unroll
        for (int db = 0; db < 4; ++db){
          bf16x8 vf = *reinterpret_cast<const bf16x8*>(
              &Vs[db * 32 + l31][kc * 16 + hi * 8]);
          o[db] = __builtin_amdgcn_mfma_f32_32x32x16_bf16(pa.v, vf, o[db], 0, 0, 0);
        }
      }
      __builtin_amdgcn_s_setprio(0);
    }
    __syncthreads();   // Ks/Vs free for next tile's ds_writes
  }

  if (nc == 1){
    // ---- final (Q<8): O /= l; write AO in (B,T,C) bf16 ----
    float inv = 1.0f / lrun;                 // this lane's q = qw + l31
    #pragma unroll
    for (int r = 0; r < 16; ++r){
      const int crow = (r & 3) + 8 * (r >> 2) + 4 * hi;
      float ir = __shfl(inv, crow, 32);
      #pragma unroll
      for (int db = 0; db < 4; ++db)
        AO[((size_t)b * T_SEQ + qw + crow) * CDIM + h * HD + db * 32 + l31] =
            f2bf(o[db][r] * ir);
    }
  } else {
    // ---- partial: unnormalized O (bf16) + m,l per row (m in log2 domain) ----
    const int slot = bh * 16 + 2 * (Q - 8) + c;
    unsigned short* OpW = Op + (size_t)slot * 128 * 128;
    #pragma unroll
    for (int r = 0; r < 16; ++r){
      const int row = wave * 32 + (r & 3) + 8 * (r >> 2) + 4 * hi;
      #pragma unroll
      for (int db = 0; db < 4; ++db)
        OpW[row * 128 + db * 32 + l31] = f2bf(o[db][r]);
    }
    if (hi == 0){
      Mp[(size_t)slot * 128 + wave * 32 + l31] = mrun;
      Lp[(size_t)slot * 128 + wave * 32 + l31] = lrun;
    }
  }
}

// ---------------- combine partials for q-blocks with nc==2 (Q=8..15) ----------------
__global__ __launch_bounds__(256) void attn_combine(
    const unsigned short* __restrict__ Op, const float* __restrict__ Mp,
    const float* __restrict__ Lp, unsigned short* __restrict__ AO)
{
  const int Q  = 8 + blockIdx.x;            // 8..15
  const int bh = blockIdx.y;
  const int b = bh / NH, h = bh % NH;
  const int slot0 = bh * 16 + 2 * (Q - 8);
  #pragma unroll
  for (int u = 0; u < 16; ++u){
    int unit = threadIdx.x + u * 256;       // 128 rows x 32 4-col groups
    int r = unit >> 5, d4 = unit & 31;
    const float m0 = Mp[(size_t)slot0 * 128 + r];
    const float m1 = Mp[(size_t)(slot0 + 1) * 128 + r];
    const float m = fmaxf(m0, m1);
    const float w0 = __builtin_amdgcn_exp2f(m0 - m);
    const float w1 = __builtin_amdgcn_exp2f(m1 - m);
    const float l = w0 * Lp[(size_t)slot0 * 128 + r]
                  + w1 * Lp[(size_t)(slot0 + 1) * 128 + r];
    const ushort4 v0 = *reinterpret_cast<const ushort4*>(
        &Op[((size_t)slot0 * 128 + r) * 128 + d4 * 4]);
    const ushort4 v1 = *reinterpret_cast<const ushort4*>(
        &Op[((size_t)(slot0 + 1) * 128 + r) * 128 + d4 * 4]);
    const float inv = 1.0f / l;
    ushort4 ov;
    ov.x = f2bf((w0 * bf2f(v0.x) + w1 * bf2f(v1.x)) * inv);
    ov.y = f2bf((w0 * bf2f(v0.y) + w1 * bf2f(v1.y)) * inv);
    ov.z = f2bf((w0 * bf2f(v0.z) + w1 * bf2f(v1.z)) * inv);
    ov.w = f2bf((w0 * bf2f(v0.w) + w1 * bf2f(v1.w)) * inv);
    *reinterpret_cast<ushort4*>(
        &AO[((size_t)b * T_SEQ + Q * 128 + r) * CDIM + h * HD + d4 * 4]) = ov;
  }
}

// ---------------- launch ----------------
extern "C" void kernel_launch(void* const* d_in, const int* in_sizes, int n_in,
                              void* d_out, int out_size, void* d_ws, size_t ws_size,
                              hipStream_t stream)
{
  (void)in_sizes; (void)n_in; (void)out_size; (void)ws_size;
  const float* x    = (const float*)d_in[0];
  const float* cosp = (const float*)d_in[1];
  const float* sinp = (const float*)d_in[2];
  const float* Wq   = (const float*)d_in[3];
  const float* Wk   = (const float*)d_in[4];
  const float* Wv   = (const float*)d_in[5];
  const float* Wo   = (const float*)d_in[6];
  float* out = (float*)d_out;

  // workspace layout: bf16 region then partials (~95 MB)
  unsigned short* xb    = (unsigned short*)d_ws;
  unsigned short* Wqkvb = xb    + (size_t)MROWS * CDIM;
  unsigned short* Wob   = Wqkvb + (size_t)NQKV * CDIM;
  unsigned short* QKVb  = Wob   + (size_t)CDIM * CDIM;
  unsigned short* Vtb   = QKVb  + (size_t)MROWS * NQKV;
  unsigned short* AO    = Vtb   + (size_t)MROWS * CDIM;
  unsigned short* Op    = AO    + (size_t)MROWS * CDIM;
  float* Mp = (float*)(Op + (size_t)NSLOT * 128 * 128);
  float* Lp = Mp + (size_t)NSLOT * 128;

  // all f32->bf16 conversions in one launch (x + 4 weight matrices)
  cvt_all<<<8448, 256, 0, stream>>>(x, Wq, Wk, Wv, Wo, xb, Wqkvb);

  // fused QKV projection + RoPE/RMSNorm(+Q-prescale) + V-transpose epilogue
  gemm_bt<1><<<dim3(MROWS / 128, NQKV / 128), 256, 0, stream>>>(
      xb, Wqkvb, QKVb, MROWS, NQKV, CDIM, cosp, sinp, Vtb);
  // causal flash attention, big-chunk split-KV -> AO (+partials)
  attn_fwd<<<576, 256, 0, stream>>>(QKVb, Vtb, AO, Op, Mp, Lp);
  attn_combine<<<dim3(8, 24), 256, 0, stream>>>(Op, Mp, Lp, AO);
  // output projection -> f32 d_out
  gemm_bt<0><<<dim3(MROWS / 128, CDIM / 128), 256, 0, stream>>>(
      AO, Wob, out, MROWS, CDIM, CDIM, nullptr, nullptr, nullptr);
}